// Round 25
// baseline (244.173 us; speedup 1.0000x reference)
//
#include <hip/hip_runtime.h>
#include <hip/hip_bf16.h>

typedef __bf16 bf16;
typedef __attribute__((ext_vector_type(8))) __bf16 bf16x8;
typedef __attribute__((ext_vector_type(4))) __bf16 bf16x4;
typedef __attribute__((ext_vector_type(4))) float f32x4;
typedef __attribute__((ext_vector_type(16))) float f32x16;

// async global->LDS: stages 16B per lane; LDS dest = uniform base + lane*16
__device__ __forceinline__ void glds16(const bf16* g, bf16* l)
{
  __builtin_amdgcn_global_load_lds(
      (const __attribute__((address_space(1))) unsigned int*)g,
      (__attribute__((address_space(3))) unsigned int*)l, 16, 0, 0);
}

__device__ __forceinline__ unsigned pk_bf16(float lo, float hi)
{
  unsigned r;
  asm("v_cvt_pk_bf16_f32 %0, %1, %2" : "=v"(r) : "v"(lo), "v"(hi));
  return r;
}
__device__ __forceinline__ void plswap(unsigned& a, unsigned& b)
{
  asm volatile("v_permlane32_swap_b32 %0, %1" : "+v"(a), "+v"(b));
}
__device__ __forceinline__ float2 swap_halves(float x)
{
  unsigned a = __float_as_uint(x), b = a;
  plswap(a, b);
  return make_float2(__uint_as_float(a), __uint_as_float(b));
}
// raw v_exp_f32: 2^x, single instruction (exp2f() libcall was +15us, round 7)
__device__ __forceinline__ float fexp2(float x)
{
  float r;
  asm("v_exp_f32 %0, %1" : "=v"(r) : "v"(x));
  return r;
}

// bijective XCD-chunked remap (m204) of a LOCAL flat id over nwg workgroups.
__device__ __forceinline__ int xcd_swz_local(int bid, int nwg)
{
  int q = nwg >> 3, r = nwg & 7;
  int xcd = bid & 7, idx = bid >> 3;
  return (xcd < r) ? (xcd * (q + 1) + idx) : (r * (q + 1) + (xcd - r) * q + idx);
}

// XCD chunk mapping with bx FAST-VARYING inside the chunk (round-17: geglu
// FETCH 70->20.7MB). Requires nwg%8==0 and (nwg/8)%gy==0 (true for all grids).
__device__ __forceinline__ void xcd_map(int bid, int nwg, int gy,
                                        int& bx, int& by)
{
  int q = nwg >> 3;
  int xcd = bid & 7, idx = bid >> 3;
  int stripe = q / gy;
  bx = xcd * stripe + idx % stripe;
  by = idx / stripe;
}

// ---------------------------------------------------------------------------
// Round-20 LDS swizzle (verified: SQ_LDS_BANK_CONFLICT 4.19M -> 0):
//   stage source chunk ^= (lane>>3)&3 ; ds_read chunk ^= (l15>>1)&3
// Round-25: s_setprio removed from lockstep GEMM bodies (T5/m190: null-to-
// negative on barrier-synced lockstep; kept in phase-split flash per m191).
// ---------------------------------------------------------------------------

// ---------------------------------------------------------------------------
// GEMM device body (4-buf, two K-tiles per barrier window) — round-20 proven.
// modes: 0 bf16(+bias); 2 bf16(acc+bias+resid); 3 = f32 acc+bias+resid
//        stored TRANSPOSED to d_out[b][c][n].
// ---------------------------------------------------------------------------
template <int BN>
__device__ __forceinline__ void gemm_dev(
    bf16* AsL, bf16* BsL,                 // 4 bufs: 128*32 and BN*32 each
    int bx, int by, long z,
    const bf16* __restrict__ A, long sAz,
    const bf16* __restrict__ B, long sBz,
    int M, int N, int K,
    void* __restrict__ Dp, long sDz, int ldd,
    const float* __restrict__ bias,
    const bf16* __restrict__ resid,
    int mode)
{
  constexpr int NI = BN / 32;
  const int tid = threadIdx.x;
  const int lane = tid & 63;
  const int wave = tid >> 6;
  const int l15 = lane & 15, lg = lane >> 4;
  const int wm = (wave & 1) << 6;
  const int wn = (BN == 128) ? ((wave >> 1) << 6) : ((wave >> 1) << 5);

  const bf16* Ab = A + z * sAz + (long)(bx * 128) * K;
  const bf16* Bb = B + z * sBz + (long)(by * BN) * K;

  const int srow = lane >> 2;
  const int schunk = (((lane & 3) ^ ((lane >> 3) & 3))) * 8;  // swizzled source
  const bf16* gA = Ab + (long)(wave * 32 + srow) * K + schunk;
  const int lAoff = wave * 1024;
  const bf16* gB;
  int lBoff;
  if (BN == 128) { gB = Bb + (long)(wave * 32 + srow) * K + schunk; lBoff = wave * 1024; }
  else           { gB = Bb + (long)(wave * 16 + srow) * K + schunk; lBoff = wave * 512; }

  const int rc = (lg ^ ((l15 >> 1) & 3)) * 8;                 // swizzled read

  f32x4 acc[4][NI] = {};

  auto STAGE = [&](int t) {
    int buf = t & 3;
    int k0 = t << 5;
    glds16(gA + k0, AsL + buf * 4096 + lAoff);
    glds16(gA + 16 * K + k0, AsL + buf * 4096 + lAoff + 512);
    glds16(gB + k0, BsL + buf * (BN * 32) + lBoff);
    if (BN == 128) glds16(gB + 16 * K + k0, BsL + buf * (BN * 32) + lBoff + 512);
  };

  auto COMPUTE = [&](int t) {
    int buf = t & 3;
    bf16x8 af[4], bfr[NI];
#pragma unroll
    for (int i = 0; i < 4; i++)
      af[i] = *(const bf16x8*)(AsL + buf * 4096 + (wm + i * 16 + l15) * 32 + rc);
#pragma unroll
    for (int i = 0; i < NI; i++)
      bfr[i] = *(const bf16x8*)(BsL + buf * (BN * 32) + (wn + i * 16 + l15) * 32 + rc);
#pragma unroll
    for (int mi = 0; mi < 4; mi++)
#pragma unroll
      for (int ni = 0; ni < NI; ni++)
        acc[mi][ni] = __builtin_amdgcn_mfma_f32_16x16x32_bf16(af[mi], bfr[ni],
                                                              acc[mi][ni], 0, 0, 0);
  };

  const int nt = K >> 5;          // even for all K used (512/768/2048)
  const int np = nt >> 1;
  STAGE(0);
  STAGE(1);

  for (int p = 0; p < np; ++p) {
    const int t0 = 2 * p;
    if (p + 1 < np) {
      STAGE(t0 + 2);
      STAGE(t0 + 3);
      if constexpr (BN == 128) asm volatile("s_waitcnt vmcnt(8)" ::: "memory");
      else                     asm volatile("s_waitcnt vmcnt(6)" ::: "memory");
    } else {
      asm volatile("s_waitcnt vmcnt(0)" ::: "memory");
    }
    __builtin_amdgcn_s_barrier();
    __builtin_amdgcn_sched_barrier(0);

    COMPUTE(t0);
    COMPUTE(t0 + 1);

    asm volatile("s_waitcnt lgkmcnt(0)" ::: "memory");
    __builtin_amdgcn_sched_barrier(0);
    __builtin_amdgcn_s_barrier();
  }

  const int gr0 = bx * 128 + wm;
  const int gc0 = by * BN + wn;

  if (mode != 3) {
#pragma unroll
    for (int ni = 0; ni < NI; ni++) {
      int gc = gc0 + ni * 16 + l15;
      float bv = bias ? bias[gc] : 0.f;
#pragma unroll
      for (int mi = 0; mi < 4; mi++) {
#pragma unroll
        for (int rr = 0; rr < 4; rr++) {
          int gr = gr0 + mi * 16 + 4 * lg + rr;
          long o = z * sDz + (long)gr * ldd + gc;
          float val = acc[mi][ni][rr] + bv;
          if (mode == 0) ((bf16*)Dp)[o] = (bf16)val;
          else           ((bf16*)Dp)[o] = (bf16)(val + (float)resid[o]);
        }
      }
    }
  } else {
    // transposed store: d_out[b][c][n] = acc + bias + resid (BN==64 path)
    float* T = (float*)AsL;                    // 64 x 68 f32 tile
    const int bb = (bx * 128) >> 11;
    const int n0 = (bx * 128) & 2047;
    float* dout = (float*)Dp;
#pragma unroll
    for (int half = 0; half < 2; half++) {
      if ((wave & 1) == half) {
#pragma unroll
        for (int ni = 0; ni < NI; ni++) {
          int cl = wn + ni * 16 + l15;
          float bv = bias ? bias[by * BN + cl] : 0.f;
#pragma unroll
          for (int mi = 0; mi < 4; mi++) {
#pragma unroll
            for (int rr = 0; rr < 4; rr++) {
              int nl = mi * 16 + 4 * lg + rr;
              int gr = gr0 + mi * 16 + 4 * lg + rr;
              float val = acc[mi][ni][rr] + bv
                        + (float)resid[(long)gr * ldd + by * BN + cl];
              T[cl * 68 + nl] = val;
            }
          }
        }
      }
      __syncthreads();
      {
        int c = tid >> 2, seg = tid & 3;
        long ob = (long)bb * 512 * 2048 + (long)(by * BN + c) * 2048
                + n0 + half * 64 + seg * 16;
#pragma unroll
        for (int j = 0; j < 4; j++) {
          float4 v = *(float4*)&T[c * 68 + seg * 16 + j * 4];
          *(float4*)(dout + ob + j * 4) = v;
        }
      }
      __syncthreads();
    }
  }
}

// standalone GEMM kernel (512-block grids: grid-limited 2/CU, pairing free)
template <int BN>
__global__ __launch_bounds__(256) void gemm_nt(
    const bf16* __restrict__ A, long sAz,
    const bf16* __restrict__ B, long sBz,
    int M, int N, int K,
    void* __restrict__ Dp, long sDz, int ldd,
    const float* __restrict__ bias,
    const bf16* __restrict__ resid,
    int mode)
{
  __shared__ bf16 As[4 * 128 * 32];
  __shared__ bf16 Bs[4 * BN * 32];
  int bx, by;
  xcd_map(blockIdx.y * gridDim.x + blockIdx.x, gridDim.x * gridDim.y,
          gridDim.y, bx, by);
  gemm_dev<BN>(As, Bs, bx, by, 0, A, sAz, B, sBz, M, N, K,
               Dp, sDz, ldd, bias, resid, mode);
}

// ---------------------------------------------------------------------------
// uber GEMM: qk | wv1 | kb | wv2 (round-20 4-buf bodies)
// ---------------------------------------------------------------------------
__global__ __launch_bounds__(256) void gemm_uber(
    const bf16* __restrict__ h,  const bf16* __restrict__ wqk1, bf16* qkb,
    const bf16* __restrict__ wv1w, bf16* vb,
    const bf16* __restrict__ ctxt, const bf16* __restrict__ wk2w, bf16* kb,
    const bf16* __restrict__ wv2w, bf16* vb2)
{
  __shared__ bf16 As[4 * 128 * 32];
  __shared__ bf16 Bs[4 * 128 * 32];
  int gid = blockIdx.x;
  if (gid < 512) {
    int bx, by;
    xcd_map(gid, 512, 8, bx, by);
    gemm_dev<128>(As, Bs, bx, by, 0, h, 0, wqk1, 0,
                  8192, 1024, 512, qkb, 0, 1024, nullptr, nullptr, 0);
  } else if (gid < 1024) {
    int l = gid - 512;
    int z = l >> 7, r = l & 127;
    gemm_dev<64>(As, Bs, r & 3, r >> 2, z, wv1w, 0, h, (long)2048 * 512,
                 512, 2048, 512, vb, (long)512 * 2048, 2048,
                 nullptr, nullptr, 0);
  } else if (gid < 1088) {
    int bx, by;
    xcd_map(gid - 1024, 64, 8, bx, by);
    gemm_dev<64>(As, Bs, bx, by, 0, ctxt, 0, wk2w, 0,
                 1024, 512, 768, kb, 0, 512, nullptr, nullptr, 0);
  } else {
    int l = gid - 1088;
    int z = l >> 4, r = l & 15;
    gemm_dev<64>(As, Bs, r & 3, r >> 2, z, wv2w, 0, ctxt, (long)256 * 768,
                 512, 256, 768, vb2, (long)512 * 256, 256,
                 nullptr, nullptr, 0);
  }
}

// ---------------------------------------------------------------------------
// prologue: weight cvt (10 segs) + x transpose (bf16 out) + ctx transpose
// ---------------------------------------------------------------------------
struct CvtPack {
  const float* src[10];
  bf16* dst[10];
  int end4[10];
};

__global__ __launch_bounds__(256) void prologue(
    CvtPack p, int total4,
    const float* __restrict__ x, bf16* __restrict__ xt,
    const float* __restrict__ ctx, bf16* __restrict__ ctxt)
{
  __shared__ float tile[32][33];
  int gid = blockIdx.x;
  const int CVT_B = 5376;
  if (gid < CVT_B) {
    int i = gid * 256 + threadIdx.x;
    if (i >= total4) return;
    int s = 0;
#pragma unroll
    for (int k = 0; k < 9; k++) s += (i >= p.end4[k]) ? 1 : 0;
    int base = s ? p.end4[s - 1] : 0;
    long j = (long)(i - base) * 4;
    f32x4 v = *(const f32x4*)(p.src[s] + j);
    bf16x4 r;
    r.x = (bf16)v.x; r.y = (bf16)v.y; r.z = (bf16)v.z; r.w = (bf16)v.w;
    *(bf16x4*)(p.dst[s] + j) = r;
  } else if (gid < CVT_B + 4096) {
    int l = gid - CVT_B;
    int bxx = l & 63, byy = (l >> 6) & 15, bz = l >> 10;
    const float* in = x + (long)bz * 512 * 2048;
    bf16* out = xt + (long)bz * 512 * 2048;
    int c0 = bxx * 32, r0 = byy * 32;
    int tx = threadIdx.x & 31, ty = threadIdx.x >> 5;
    for (int i = ty; i < 32; i += 8)
      tile[i][tx] = in[(long)(r0 + i) * 2048 + c0 + tx];
    __syncthreads();
    for (int i = ty; i < 32; i += 8)
      out[(long)(c0 + i) * 512 + r0 + tx] = (bf16)tile[tx][i];
  } else {
    int l = gid - CVT_B - 4096;
    int bxx = l & 7, byy = (l >> 3) % 24, bz = l / 192;
    const float* in = ctx + (long)bz * 768 * 256;
    bf16* out = ctxt + (long)bz * 768 * 256;
    int c0 = bxx * 32, r0 = byy * 32;
    int tx = threadIdx.x & 31, ty = threadIdx.x >> 5;
    for (int i = ty; i < 32; i += 8)
      tile[i][tx] = in[(long)(r0 + i) * 256 + c0 + tx];
    __syncthreads();
    for (int i = ty; i < 32; i += 8)
      out[(long)(c0 + i) * 768 + r0 + tx] = (bf16)tile[tx][i];
  }
}

// ---------------------------------------------------------------------------
// LayerNorm rows of 512, bf16 in (vectorized bf16x8), bf16 out; 1 wave/row
// ---------------------------------------------------------------------------
__global__ __launch_bounds__(256) void ln_rows(const bf16* __restrict__ x,
                                               const float* __restrict__ g,
                                               bf16* __restrict__ out)
{
  int row = blockIdx.x * 4 + (threadIdx.x >> 6);
  int lane = threadIdx.x & 63;
  bf16x8 v = *(const bf16x8*)(x + (long)row * 512 + lane * 8);
  float f[8];
#pragma unroll
  for (int i = 0; i < 8; i++) f[i] = (float)v[i];
  float s = ((f[0] + f[1]) + (f[2] + f[3])) + ((f[4] + f[5]) + (f[6] + f[7]));
  float q = ((f[0]*f[0] + f[1]*f[1]) + (f[2]*f[2] + f[3]*f[3]))
          + ((f[4]*f[4] + f[5]*f[5]) + (f[6]*f[6] + f[7]*f[7]));
#pragma unroll
  for (int off = 32; off; off >>= 1) {
    s += __shfl_xor(s, off);
    q += __shfl_xor(q, off);
  }
  float mean = s * (1.f / 512.f);
  float var  = q * (1.f / 512.f) - mean * mean;
  float rs = rsqrtf(var + 1e-5f);
  f32x4 ga = *(const f32x4*)(g + lane * 8);
  f32x4 gb = *(const f32x4*)(g + lane * 8 + 4);
  bf16x8 r;
#pragma unroll
  for (int i = 0; i < 4; i++) r[i] = (bf16)((f[i] - mean) * rs * ga[i]);
#pragma unroll
  for (int i = 0; i < 4; i++) r[4 + i] = (bf16)((f[4 + i] - mean) * rs * gb[i]);
  *(bf16x8*)(out + (long)row * 512 + lane * 8) = r;
}

// ---------------------------------------------------------------------------
// Fused GEGLU dual-GEMM v4 (3-buf depth-2, swizzled; setprio removed r25)
// ---------------------------------------------------------------------------
__global__ __launch_bounds__(256) void gemm_geglu(
    const bf16* __restrict__ A,
    const bf16* __restrict__ WH, const bf16* __restrict__ WG,
    const float* __restrict__ bH, const float* __restrict__ bG,
    bf16* __restrict__ D, int K)
{
  __shared__ bf16 As[3][128 * 32];
  __shared__ bf16 Hs[3][64 * 32];
  __shared__ bf16 Gs[3][64 * 32];
  const int tid = threadIdx.x;
  const int lane = tid & 63;
  const int wave = tid >> 6;
  const int l15 = lane & 15, lg = lane >> 4;
  const int wm = (wave & 1) << 6;
  const int wn = (wave >> 1) << 5;

  int bx, by;
  xcd_map(blockIdx.y * gridDim.x + blockIdx.x, gridDim.x * gridDim.y,
          gridDim.y, bx, by);

  const bf16* Ab = A + (long)(bx * 128) * K;
  const bf16* Hb = WH + (long)(by * 64) * K;
  const bf16* Gb = WG + (long)(by * 64) * K;

  const int srow = lane >> 2;
  const int schunk = (((lane & 3) ^ ((lane >> 3) & 3))) * 8;  // swizzled source
  const bf16* gA = Ab + (long)(wave * 32 + srow) * K + schunk;
  const bf16* gH = Hb + (long)(wave * 16 + srow) * K + schunk;
  const bf16* gG = Gb + (long)(wave * 16 + srow) * K + schunk;
  const int lAoff = wave * 1024, lBoff = wave * 512;

  const int rc = (lg ^ ((l15 >> 1) & 3)) * 8;                 // swizzled read

  f32x4 aH[4][2] = {}, aG[4][2] = {};

  auto STAGE = [&](int buf, int t) {
    int k0 = t << 5;
    glds16(gA + k0, &As[buf][lAoff]);
    glds16(gA + 16 * K + k0, &As[buf][lAoff + 512]);
    glds16(gH + k0, &Hs[buf][lBoff]);
    glds16(gG + k0, &Gs[buf][lBoff]);
  };

  const int nt = K >> 5;
  STAGE(0, 0);
  STAGE(1, 1);

  int cur = 0;
  for (int t = 0; t < nt; ++t) {
    if (t + 2 < nt) {
      int sb = cur + 2; if (sb >= 3) sb -= 3;
      STAGE(sb, t + 2);
      asm volatile("s_waitcnt vmcnt(8)" ::: "memory");
    } else if (t + 2 == nt) {
      asm volatile("s_waitcnt vmcnt(4)" ::: "memory");
    } else {
      asm volatile("s_waitcnt vmcnt(0)" ::: "memory");
    }
    __builtin_amdgcn_s_barrier();
    __builtin_amdgcn_sched_barrier(0);

    bf16x8 af[4], hf[2], gf[2];
#pragma unroll
    for (int i = 0; i < 4; i++)
      af[i] = *(const bf16x8*)(&As[cur][(wm + i * 16 + l15) * 32 + rc]);
#pragma unroll
    for (int i = 0; i < 2; i++) {
      hf[i] = *(const bf16x8*)(&Hs[cur][(wn + i * 16 + l15) * 32 + rc]);
      gf[i] = *(const bf16x8*)(&Gs[cur][(wn + i * 16 + l15) * 32 + rc]);
    }
#pragma unroll
    for (int mi = 0; mi < 4; mi++)
#pragma unroll
      for (int ni = 0; ni < 2; ni++) {
        aH[mi][ni] = __builtin_amdgcn_mfma_f32_16x16x32_bf16(af[mi], hf[ni],
                                                             aH[mi][ni], 0, 0, 0);
        aG[mi][ni] = __builtin_amdgcn_mfma_f32_16x16x32_bf16(af[mi], gf[ni],
                                                             aG[mi][ni], 0, 0, 0);
      }
    asm volatile("s_waitcnt lgkmcnt(0)" ::: "memory");
    __builtin_amdgcn_sched_barrier(0);
    __builtin_amdgcn_s_barrier();
    cur = (cur == 2) ? 0 : cur + 1;
  }

  const int gr0 = bx * 128 + wm;
  const int gc0 = by * 64 + wn;
#pragma unroll
  for (int ni = 0; ni < 2; ni++) {
    int gc = gc0 + ni * 16 + l15;
    float bh = bH[gc], bg = bG[gc];
#pragma unroll
    for (int mi = 0; mi < 4; mi++) {
#pragma unroll
      for (int rr = 0; rr < 4; rr++) {
        int gr = gr0 + mi * 16 + 4 * lg + rr;
        float hv = aH[mi][ni][rr] + bh;
        float gv = aG[mi][ni][rr] + bg;
        float ge = 0.5f * gv * (1.f + erff(gv * 0.70710678118654752f));
        D[(long)gr * 2048 + gc] = (bf16)(hv * ge);
      }
    }
  }
}

// ---------------------------------------------------------------------------
// Flash attention v9 (round-16): no-max softmax, 4 waves, two KV tiles/window
// (setprio KEPT: phase-split schedule = T5's positive regime, m191)
// ---------------------------------------------------------------------------
__global__ __launch_bounds__(256) void flash_attn(
    const bf16* __restrict__ Q, int ldq,
    const bf16* __restrict__ Kt, int ldk,
    const bf16* __restrict__ V,
    bf16* __restrict__ O,
    int Nq, int Nkv)
{
  int wid = xcd_swz_local(blockIdx.y * gridDim.x + blockIdx.x,
                          gridDim.x * gridDim.y);
  const int i0 = (wid % gridDim.x) * 128;
  const int bh = wid / gridDim.x;
  const int b = bh >> 3, h = bh & 7;
  const int lane = threadIdx.x & 63, wave = threadIdx.x >> 6;
  const int l31 = lane & 31, hi = lane >> 5;

  __shared__ bf16 Ks[4][64 * 64];
  __shared__ bf16 Vs[4][64 * 64];

  const bf16* Qb = Q + ((long)b * Nq + i0 + wave * 32) * ldq + h * 64;
  const bf16* Kb = Kt + (long)b * Nkv * ldk + h * 64;
  const bf16* Vb = V + ((long)b * 512 + h * 64) * Nkv;
  bf16* Ob = O + ((long)b * Nq + i0 + wave * 32) * 512 + h * 64;

  const float QSC = 0.125f * 1.44269504f;
  bf16x8 qf[4];
#pragma unroll
  for (int ds = 0; ds < 4; ds++) {
    qf[ds] = *(const bf16x8*)(Qb + (long)l31 * ldq + ds * 16 + 8 * hi);
#pragma unroll
    for (int e = 0; e < 8; e++) qf[ds][e] = (bf16)((float)qf[ds][e] * QSC);
  }

  const int srow = lane >> 3;
  const int schk = ((lane & 7) ^ srow) * 8;
  const int r0 = wave * 16;

  const int nt = Nkv >> 6;
  const int np = nt >> 1;

  auto STAGE = [&](int buf, long j) {
    glds16(Kb + (j + r0 + srow) * ldk + schk, &Ks[buf][r0 * 64]);
    glds16(Kb + (j + r0 + 8 + srow) * ldk + schk, &Ks[buf][(r0 + 8) * 64]);
    glds16(Vb + (long)(r0 + srow) * Nkv + j + schk, &Vs[buf][r0 * 64]);
    glds16(Vb + (long)(r0 + 8 + srow) * Nkv + j + schk, &Vs[buf][(r0 + 8) * 64]);
  };

  f32x16 ot0 = {}, ot1 = {};
  float lrun = 0.f;

  auto QK = [&](f32x16& s0, f32x16& s1, int buf) {
    s0 = (f32x16){}; s1 = (f32x16){};
    __builtin_amdgcn_s_setprio(1);
#pragma unroll
    for (int ds = 0; ds < 4; ds++) {
      int ch = 2 * ds + hi;
      bf16x8 k0 = *(const bf16x8*)(&Ks[buf][l31 * 64 + ((ch ^ (l31 & 7)) * 8)]);
      bf16x8 k1 = *(const bf16x8*)(&Ks[buf][(32 + l31) * 64 + ((ch ^ (l31 & 7)) * 8)]);
      s0 = __builtin_amdgcn_mfma_f32_32x32x16_bf16(k0, qf[ds], s0, 0, 0, 0);
      s1 = __builtin_amdgcn_mfma_f32_32x32x16_bf16(k1, qf[ds], s1, 0, 0, 0);
    }
    __builtin_amdgcn_s_setprio(0);
  };

  auto SMPV = [&](f32x16& st0, f32x16& st1, int buf) {
    float sm[8];
#pragma unroll
    for (int r = 0; r < 16; r++) {
      st0[r] = fexp2(st0[r]);
      st1[r] = fexp2(st1[r]);
    }
#pragma unroll
    for (int r = 0; r < 8; r++)
      sm[r] = (st0[r] + st0[r + 8]) + (st1[r] + st1[r + 8]);
#pragma unroll
    for (int off = 4; off; off >>= 1)
#pragma unroll
      for (int r = 0; r < off; r++) sm[r] += sm[r + off];
    { float2 pr = swap_halves(sm[0]); lrun += pr.x + pr.y; }

    __builtin_amdgcn_s_setprio(1);
#pragma unroll
    for (int c = 0; c < 4; c++) {
      const f32x16& sv = (c < 2) ? st0 : st1;
      const int base = (c & 1) * 8;
      unsigned a0 = pk_bf16(sv[base + 0], sv[base + 1]);
      unsigned b0 = pk_bf16(sv[base + 4], sv[base + 5]);
      unsigned a1 = pk_bf16(sv[base + 2], sv[base + 3]);
      unsigned b1 = pk_bf16(sv[base + 6], sv[base + 7]);
      plswap(a0, b0);
      plswap(a1, b1);
      uint4 wd = make_uint4(a0, a1, b0, b1);
      bf16x8 pB = *(bf16x8*)&wd;
      int ch = 2 * c + hi;
#pragma unroll
      for (int dt = 0; dt < 2; dt++) {
        int r = dt * 32 + l31;
        bf16x8 vf = *(const bf16x8*)(&Vs[buf][r * 64 + ((ch ^ (l31 & 7)) * 8)]);
        if (dt == 0) ot0 = __builtin_amdgcn_mfma_f32_32x32x16_bf16(vf, pB, ot0, 0, 0, 0);
        else         ot1 = __builtin_amdgcn_mfma_f32_32x32x16_bf16(vf, pB, ot1, 0, 0, 0);
      }
    }
    __builtin_amdgcn_s_setprio(0);
  };

  STAGE(0, 0);
  STAGE(1, 64);

  for (int p = 0; p < np; ++p) {
    const int t0 = 2 * p;
    if (p + 1 < np) {
      STAGE((t0 + 2) & 3, (long)(t0 + 2) * 64);
      STAGE((t0 + 3) & 3, (long)(t0 + 3) * 64);
      asm volatile("s_waitcnt vmcnt(8)");
    } else {
      asm volatile("s_waitcnt vmcnt(0)");
    }
    __builtin_amdgcn_s_barrier();
    __builtin_amdgcn_sched_barrier(0);

    f32x16 sA0, sA1, sB0, sB1;
    QK(sA0, sA1, t0 & 3);
    QK(sB0, sB1, (t0 + 1) & 3);
    SMPV(sA0, sA1, t0 & 3);
    SMPV(sB0, sB1, (t0 + 1) & 3);

    asm volatile("s_waitcnt lgkmcnt(0)");
    __builtin_amdgcn_s_barrier();
  }

  __syncthreads();
  bf16* Ow = &Ks[0][0] + wave * 2048;
  float inv = 1.0f / lrun;
#pragma unroll
  for (int dt = 0; dt < 2; dt++) {
#pragma unroll
    for (int r = 0; r < 16; r++) {
      int d = dt * 32 + (r & 3) + 8 * (r >> 2) + 4 * hi;
      float v = (dt == 0 ? ot0[r] : ot1[r]) * inv;
      Ow[l31 * 64 + (((d >> 3) ^ (l31 & 7)) * 8) + (d & 7)] = (bf16)v;
    }
  }
  __syncthreads();
#pragma unroll
  for (int i = 0; i < 4; i++) {
    int ch = hi * 4 + i;
    uint4 wd = *(const uint4*)(&Ow[l31 * 64 + ((ch ^ (l31 & 7)) * 8)]);
    *(uint4*)(Ob + (long)l31 * 512 + ch * 8) = wd;
  }
}

// ---------------------------------------------------------------------------
// host
// ---------------------------------------------------------------------------
template <int BN>
static void launch_gemm(const bf16* A, long sAz, const bf16* B, long sBz,
                        int M, int N, int K, void* D, long sDz, int ldd,
                        const float* bias, const bf16* resid,
                        int mode, hipStream_t stream)
{
  gemm_nt<BN><<<dim3(M / 128, N / BN), dim3(256), 0, stream>>>(
      A, sAz, B, sBz, M, N, K, D, sDz, ldd, bias, resid, mode);
}

extern "C" void kernel_launch(void* const* d_in, const int* in_sizes, int n_in,
                              void* d_out, int out_size, void* d_ws, size_t ws_size,
                              hipStream_t stream)
{
  (void)in_sizes; (void)n_in; (void)out_size; (void)ws_size;
  const float* x     = (const float*)d_in[0];
  const float* ctx   = (const float*)d_in[1];
  const float* g1    = (const float*)d_in[2];
  const float* Wq1f  = (const float*)d_in[3];
  const float* Wk1f  = (const float*)d_in[4];
  const float* Wv1f  = (const float*)d_in[5];
  const float* Wo1f  = (const float*)d_in[6];
  const float* bo1   = (const float*)d_in[7];
  const float* g2    = (const float*)d_in[8];
  const float* Wq2f  = (const float*)d_in[9];
  const float* Wk2f  = (const float*)d_in[10];
  const float* Wv2f  = (const float*)d_in[11];
  const float* Wo2f  = (const float*)d_in[12];
  const float* bo2   = (const float*)d_in[13];
  const float* g3    = (const float*)d_in[14];
  const float* Wff1f = (const float*)d_in[15];
  const float* bff1  = (const float*)d_in[16];
  const float* Wff2f = (const float*)d_in[17];
  const float* bff2  = (const float*)d_in[18];

  char* wsp = (char*)d_ws;
  size_t off = 0;
  auto alloc = [&](size_t bytes) -> void* {
    void* p = wsp + off;
    off += (bytes + 255) & ~(size_t)255;
    return p;
  };

  bf16* xt    = (bf16*)alloc((size_t)8192 * 512 * 2);   // residual stream bf16
  bf16* x2    = (bf16*)alloc((size_t)8192 * 512 * 2);
  bf16* h     = (bf16*)alloc((size_t)8192 * 512 * 2);
  bf16* qkb   = (bf16*)alloc((size_t)8192 * 1024 * 2);
  bf16* qb    = (bf16*)alloc((size_t)8192 * 512 * 2);
  bf16* kb    = (bf16*)alloc((size_t)1024 * 512 * 2);
  bf16* vb    = (bf16*)alloc((size_t)8192 * 512 * 2);
  bf16* vb2   = (bf16*)alloc((size_t)1024 * 512 * 2);
  bf16* ao    = (bf16*)alloc((size_t)8192 * 512 * 2);
  bf16* ctxt  = (bf16*)alloc((size_t)1024 * 768 * 2);
  bf16* actb  = (bf16*)alloc((size_t)8192 * 2048 * 2);
  bf16* wqk1  = (bf16*)alloc((size_t)524288 * 2);
  bf16* wv1   = (bf16*)alloc((size_t)262144 * 2);
  bf16* wo1   = (bf16*)alloc((size_t)262144 * 2);
  bf16* wq2   = (bf16*)alloc((size_t)262144 * 2);
  bf16* wk2   = (bf16*)alloc((size_t)393216 * 2);
  bf16* wv2   = (bf16*)alloc((size_t)393216 * 2);
  bf16* wo2   = (bf16*)alloc((size_t)262144 * 2);
  bf16* wff1  = (bf16*)alloc((size_t)2097152 * 2);
  bf16* wff2  = (bf16*)alloc((size_t)1048576 * 2);

  {
    CvtPack p;
    const float* s[10] = {Wq1f, Wk1f, Wv1f, Wo1f, Wq2f, Wk2f, Wv2f, Wo2f, Wff1f, Wff2f};
    bf16* d[10] = {wqk1, wqk1 + 262144, wv1, wo1, wq2, wk2, wv2, wo2, wff1, wff2};
    int n[10] = {262144, 262144, 262144, 262144, 262144, 393216, 393216, 262144,
                 2097152, 1048576};
    int cum = 0;
    for (int i = 0; i < 10; i++) {
      p.src[i] = s[i]; p.dst[i] = d[i];
      cum += n[i] / 4; p.end4[i] = cum;
    }
    prologue<<<dim3(10240), dim3(256), 0, stream>>>(p, cum, x, xt, ctx, ctxt);
  }

  // ---- block 1: self attention (+ hoisted cross K/V) ----
  ln_rows<<<dim3(2048), dim3(256), 0, stream>>>(xt, g1, h);
  gemm_uber<<<dim3(1152), dim3(256), 0, stream>>>(
      h, wqk1, qkb, wv1, vb, ctxt, wk2, kb, wv2, vb2);
  flash_attn<<<dim3(16, 32), dim3(256), 0, stream>>>(qkb, 1024, qkb + 512, 1024,
                                                     vb, ao, 2048, 2048);
  launch_gemm<64>(ao, 0, wo1, 0, 8192, 512, 512, x2, 0, 512,
                  bo1, xt, 2, stream);

  // ---- block 2: cross attention ----
  ln_rows<<<dim3(2048), dim3(256), 0, stream>>>(x2, g2, h);
  launch_gemm<64>(h, 0, wq2, 0, 8192, 512, 512, qb, 0, 512,
                  nullptr, nullptr, 0, stream);
  flash_attn<<<dim3(16, 32), dim3(256), 0, stream>>>(qb, 512, kb, 512,
                                                     vb2, ao, 2048, 256);
  launch_gemm<64>(ao, 0, wo2, 0, 8192, 512, 512, x2, 0, 512,
                  bo2, x2, 2, stream);

  // ---- block 3: GEGLU FF; ff2 stores transposed directly to d_out ----
  ln_rows<<<dim3(2048), dim3(256), 0, stream>>>(x2, g3, h);
  gemm_geglu<<<dim3(64, 32), dim3(256), 0, stream>>>(
      h, wff1, wff1 + (long)2048 * 512, bff1, bff1 + 2048, actb, 512);
  launch_gemm<64>(actb, 0, wff2, 0, 8192, 512, 2048, d_out, 0, 512,
                  bff2, x2, 3, stream);
}

// Round 26
// 243.431 us; speedup vs baseline: 1.0030x; 1.0030x over previous
//
#include <hip/hip_runtime.h>
#include <hip/hip_bf16.h>

typedef __bf16 bf16;
typedef __attribute__((ext_vector_type(8))) __bf16 bf16x8;
typedef __attribute__((ext_vector_type(4))) __bf16 bf16x4;
typedef __attribute__((ext_vector_type(4))) float f32x4;
typedef __attribute__((ext_vector_type(16))) float f32x16;

// async global->LDS: stages 16B per lane; LDS dest = uniform base + lane*16
__device__ __forceinline__ void glds16(const bf16* g, bf16* l)
{
  __builtin_amdgcn_global_load_lds(
      (const __attribute__((address_space(1))) unsigned int*)g,
      (__attribute__((address_space(3))) unsigned int*)l, 16, 0, 0);
}

__device__ __forceinline__ unsigned pk_bf16(float lo, float hi)
{
  unsigned r;
  asm("v_cvt_pk_bf16_f32 %0, %1, %2" : "=v"(r) : "v"(lo), "v"(hi));
  return r;
}
__device__ __forceinline__ void plswap(unsigned& a, unsigned& b)
{
  asm volatile("v_permlane32_swap_b32 %0, %1" : "+v"(a), "+v"(b));
}
__device__ __forceinline__ float2 swap_halves(float x)
{
  unsigned a = __float_as_uint(x), b = a;
  plswap(a, b);
  return make_float2(__uint_as_float(a), __uint_as_float(b));
}
// raw v_exp_f32: 2^x, single instruction (exp2f() libcall was +15us, round 7)
__device__ __forceinline__ float fexp2(float x)
{
  float r;
  asm("v_exp_f32 %0, %1" : "=v"(r) : "v"(x));
  return r;
}

// bijective XCD-chunked remap (m204) of a LOCAL flat id over nwg workgroups.
__device__ __forceinline__ int xcd_swz_local(int bid, int nwg)
{
  int q = nwg >> 3, r = nwg & 7;
  int xcd = bid & 7, idx = bid >> 3;
  return (xcd < r) ? (xcd * (q + 1) + idx) : (r * (q + 1) + (xcd - r) * q + idx);
}

// XCD chunk mapping with bx FAST-VARYING inside the chunk (round-17: geglu
// FETCH 70->20.7MB). Requires nwg%8==0 and (nwg/8)%gy==0 (true for all grids).
__device__ __forceinline__ void xcd_map(int bid, int nwg, int gy,
                                        int& bx, int& by)
{
  int q = nwg >> 3;
  int xcd = bid & 7, idx = bid >> 3;
  int stripe = q / gy;
  bx = xcd * stripe + idx % stripe;
  by = idx / stripe;
}

// ---------------------------------------------------------------------------
// Round-20 LDS swizzle (verified: SQ_LDS_BANK_CONFLICT 4.19M -> 0):
//   stage source chunk ^= (lane>>3)&3 ; ds_read chunk ^= (l15>>1)&3
// Round-26: setprio RESTORED (r25 removal was null-to-negative: 244.2 vs
// 242.9/243.1 — multi-block residency gives weak role-diversity, T5 regime).
// ---------------------------------------------------------------------------

// ---------------------------------------------------------------------------
// GEMM device body (4-buf, two K-tiles per barrier window) — round-20 proven.
// modes: 0 bf16(+bias); 2 bf16(acc+bias+resid); 3 = f32 acc+bias+resid
//        stored TRANSPOSED to d_out[b][c][n].
// ---------------------------------------------------------------------------
template <int BN>
__device__ __forceinline__ void gemm_dev(
    bf16* AsL, bf16* BsL,                 // 4 bufs: 128*32 and BN*32 each
    int bx, int by, long z,
    const bf16* __restrict__ A, long sAz,
    const bf16* __restrict__ B, long sBz,
    int M, int N, int K,
    void* __restrict__ Dp, long sDz, int ldd,
    const float* __restrict__ bias,
    const bf16* __restrict__ resid,
    int mode)
{
  constexpr int NI = BN / 32;
  const int tid = threadIdx.x;
  const int lane = tid & 63;
  const int wave = tid >> 6;
  const int l15 = lane & 15, lg = lane >> 4;
  const int wm = (wave & 1) << 6;
  const int wn = (BN == 128) ? ((wave >> 1) << 6) : ((wave >> 1) << 5);

  const bf16* Ab = A + z * sAz + (long)(bx * 128) * K;
  const bf16* Bb = B + z * sBz + (long)(by * BN) * K;

  const int srow = lane >> 2;
  const int schunk = (((lane & 3) ^ ((lane >> 3) & 3))) * 8;  // swizzled source
  const bf16* gA = Ab + (long)(wave * 32 + srow) * K + schunk;
  const int lAoff = wave * 1024;
  const bf16* gB;
  int lBoff;
  if (BN == 128) { gB = Bb + (long)(wave * 32 + srow) * K + schunk; lBoff = wave * 1024; }
  else           { gB = Bb + (long)(wave * 16 + srow) * K + schunk; lBoff = wave * 512; }

  const int rc = (lg ^ ((l15 >> 1) & 3)) * 8;                 // swizzled read

  f32x4 acc[4][NI] = {};

  auto STAGE = [&](int t) {
    int buf = t & 3;
    int k0 = t << 5;
    glds16(gA + k0, AsL + buf * 4096 + lAoff);
    glds16(gA + 16 * K + k0, AsL + buf * 4096 + lAoff + 512);
    glds16(gB + k0, BsL + buf * (BN * 32) + lBoff);
    if (BN == 128) glds16(gB + 16 * K + k0, BsL + buf * (BN * 32) + lBoff + 512);
  };

  auto COMPUTE = [&](int t) {
    int buf = t & 3;
    bf16x8 af[4], bfr[NI];
#pragma unroll
    for (int i = 0; i < 4; i++)
      af[i] = *(const bf16x8*)(AsL + buf * 4096 + (wm + i * 16 + l15) * 32 + rc);
#pragma unroll
    for (int i = 0; i < NI; i++)
      bfr[i] = *(const bf16x8*)(BsL + buf * (BN * 32) + (wn + i * 16 + l15) * 32 + rc);
    __builtin_amdgcn_s_setprio(1);
#pragma unroll
    for (int mi = 0; mi < 4; mi++)
#pragma unroll
      for (int ni = 0; ni < NI; ni++)
        acc[mi][ni] = __builtin_amdgcn_mfma_f32_16x16x32_bf16(af[mi], bfr[ni],
                                                              acc[mi][ni], 0, 0, 0);
    __builtin_amdgcn_s_setprio(0);
  };

  const int nt = K >> 5;          // even for all K used (512/768/2048)
  const int np = nt >> 1;
  STAGE(0);
  STAGE(1);

  for (int p = 0; p < np; ++p) {
    const int t0 = 2 * p;
    if (p + 1 < np) {
      STAGE(t0 + 2);
      STAGE(t0 + 3);
      if constexpr (BN == 128) asm volatile("s_waitcnt vmcnt(8)" ::: "memory");
      else                     asm volatile("s_waitcnt vmcnt(6)" ::: "memory");
    } else {
      asm volatile("s_waitcnt vmcnt(0)" ::: "memory");
    }
    __builtin_amdgcn_s_barrier();
    __builtin_amdgcn_sched_barrier(0);

    COMPUTE(t0);
    COMPUTE(t0 + 1);

    asm volatile("s_waitcnt lgkmcnt(0)" ::: "memory");
    __builtin_amdgcn_sched_barrier(0);
    __builtin_amdgcn_s_barrier();
  }

  const int gr0 = bx * 128 + wm;
  const int gc0 = by * BN + wn;

  if (mode != 3) {
#pragma unroll
    for (int ni = 0; ni < NI; ni++) {
      int gc = gc0 + ni * 16 + l15;
      float bv = bias ? bias[gc] : 0.f;
#pragma unroll
      for (int mi = 0; mi < 4; mi++) {
#pragma unroll
        for (int rr = 0; rr < 4; rr++) {
          int gr = gr0 + mi * 16 + 4 * lg + rr;
          long o = z * sDz + (long)gr * ldd + gc;
          float val = acc[mi][ni][rr] + bv;
          if (mode == 0) ((bf16*)Dp)[o] = (bf16)val;
          else           ((bf16*)Dp)[o] = (bf16)(val + (float)resid[o]);
        }
      }
    }
  } else {
    // transposed store: d_out[b][c][n] = acc + bias + resid (BN==64 path)
    float* T = (float*)AsL;                    // 64 x 68 f32 tile
    const int bb = (bx * 128) >> 11;
    const int n0 = (bx * 128) & 2047;
    float* dout = (float*)Dp;
#pragma unroll
    for (int half = 0; half < 2; half++) {
      if ((wave & 1) == half) {
#pragma unroll
        for (int ni = 0; ni < NI; ni++) {
          int cl = wn + ni * 16 + l15;
          float bv = bias ? bias[by * BN + cl] : 0.f;
#pragma unroll
          for (int mi = 0; mi < 4; mi++) {
#pragma unroll
            for (int rr = 0; rr < 4; rr++) {
              int nl = mi * 16 + 4 * lg + rr;
              int gr = gr0 + mi * 16 + 4 * lg + rr;
              float val = acc[mi][ni][rr] + bv
                        + (float)resid[(long)gr * ldd + by * BN + cl];
              T[cl * 68 + nl] = val;
            }
          }
        }
      }
      __syncthreads();
      {
        int c = tid >> 2, seg = tid & 3;
        long ob = (long)bb * 512 * 2048 + (long)(by * BN + c) * 2048
                + n0 + half * 64 + seg * 16;
#pragma unroll
        for (int j = 0; j < 4; j++) {
          float4 v = *(float4*)&T[c * 68 + seg * 16 + j * 4];
          *(float4*)(dout + ob + j * 4) = v;
        }
      }
      __syncthreads();
    }
  }
}

// standalone GEMM kernel (512-block grids: grid-limited 2/CU, pairing free)
template <int BN>
__global__ __launch_bounds__(256) void gemm_nt(
    const bf16* __restrict__ A, long sAz,
    const bf16* __restrict__ B, long sBz,
    int M, int N, int K,
    void* __restrict__ Dp, long sDz, int ldd,
    const float* __restrict__ bias,
    const bf16* __restrict__ resid,
    int mode)
{
  __shared__ bf16 As[4 * 128 * 32];
  __shared__ bf16 Bs[4 * BN * 32];
  int bx, by;
  xcd_map(blockIdx.y * gridDim.x + blockIdx.x, gridDim.x * gridDim.y,
          gridDim.y, bx, by);
  gemm_dev<BN>(As, Bs, bx, by, 0, A, sAz, B, sBz, M, N, K,
               Dp, sDz, ldd, bias, resid, mode);
}

// ---------------------------------------------------------------------------
// uber GEMM: qk | wv1 | kb | wv2 (round-20 4-buf bodies)
// ---------------------------------------------------------------------------
__global__ __launch_bounds__(256) void gemm_uber(
    const bf16* __restrict__ h,  const bf16* __restrict__ wqk1, bf16* qkb,
    const bf16* __restrict__ wv1w, bf16* vb,
    const bf16* __restrict__ ctxt, const bf16* __restrict__ wk2w, bf16* kb,
    const bf16* __restrict__ wv2w, bf16* vb2)
{
  __shared__ bf16 As[4 * 128 * 32];
  __shared__ bf16 Bs[4 * 128 * 32];
  int gid = blockIdx.x;
  if (gid < 512) {
    int bx, by;
    xcd_map(gid, 512, 8, bx, by);
    gemm_dev<128>(As, Bs, bx, by, 0, h, 0, wqk1, 0,
                  8192, 1024, 512, qkb, 0, 1024, nullptr, nullptr, 0);
  } else if (gid < 1024) {
    int l = gid - 512;
    int z = l >> 7, r = l & 127;
    gemm_dev<64>(As, Bs, r & 3, r >> 2, z, wv1w, 0, h, (long)2048 * 512,
                 512, 2048, 512, vb, (long)512 * 2048, 2048,
                 nullptr, nullptr, 0);
  } else if (gid < 1088) {
    int bx, by;
    xcd_map(gid - 1024, 64, 8, bx, by);
    gemm_dev<64>(As, Bs, bx, by, 0, ctxt, 0, wk2w, 0,
                 1024, 512, 768, kb, 0, 512, nullptr, nullptr, 0);
  } else {
    int l = gid - 1088;
    int z = l >> 4, r = l & 15;
    gemm_dev<64>(As, Bs, r & 3, r >> 2, z, wv2w, 0, ctxt, (long)256 * 768,
                 512, 256, 768, vb2, (long)512 * 256, 256,
                 nullptr, nullptr, 0);
  }
}

// ---------------------------------------------------------------------------
// prologue: weight cvt (10 segs) + x transpose (bf16 out) + ctx transpose
// ---------------------------------------------------------------------------
struct CvtPack {
  const float* src[10];
  bf16* dst[10];
  int end4[10];
};

__global__ __launch_bounds__(256) void prologue(
    CvtPack p, int total4,
    const float* __restrict__ x, bf16* __restrict__ xt,
    const float* __restrict__ ctx, bf16* __restrict__ ctxt)
{
  __shared__ float tile[32][33];
  int gid = blockIdx.x;
  const int CVT_B = 5376;
  if (gid < CVT_B) {
    int i = gid * 256 + threadIdx.x;
    if (i >= total4) return;
    int s = 0;
#pragma unroll
    for (int k = 0; k < 9; k++) s += (i >= p.end4[k]) ? 1 : 0;
    int base = s ? p.end4[s - 1] : 0;
    long j = (long)(i - base) * 4;
    f32x4 v = *(const f32x4*)(p.src[s] + j);
    bf16x4 r;
    r.x = (bf16)v.x; r.y = (bf16)v.y; r.z = (bf16)v.z; r.w = (bf16)v.w;
    *(bf16x4*)(p.dst[s] + j) = r;
  } else if (gid < CVT_B + 4096) {
    int l = gid - CVT_B;
    int bxx = l & 63, byy = (l >> 6) & 15, bz = l >> 10;
    const float* in = x + (long)bz * 512 * 2048;
    bf16* out = xt + (long)bz * 512 * 2048;
    int c0 = bxx * 32, r0 = byy * 32;
    int tx = threadIdx.x & 31, ty = threadIdx.x >> 5;
    for (int i = ty; i < 32; i += 8)
      tile[i][tx] = in[(long)(r0 + i) * 2048 + c0 + tx];
    __syncthreads();
    for (int i = ty; i < 32; i += 8)
      out[(long)(c0 + i) * 512 + r0 + tx] = (bf16)tile[tx][i];
  } else {
    int l = gid - CVT_B - 4096;
    int bxx = l & 7, byy = (l >> 3) % 24, bz = l / 192;
    const float* in = ctx + (long)bz * 768 * 256;
    bf16* out = ctxt + (long)bz * 768 * 256;
    int c0 = bxx * 32, r0 = byy * 32;
    int tx = threadIdx.x & 31, ty = threadIdx.x >> 5;
    for (int i = ty; i < 32; i += 8)
      tile[i][tx] = in[(long)(r0 + i) * 256 + c0 + tx];
    __syncthreads();
    for (int i = ty; i < 32; i += 8)
      out[(long)(c0 + i) * 768 + r0 + tx] = (bf16)tile[tx][i];
  }
}

// ---------------------------------------------------------------------------
// LayerNorm rows of 512, bf16 in (vectorized bf16x8), bf16 out; 1 wave/row
// ---------------------------------------------------------------------------
__global__ __launch_bounds__(256) void ln_rows(const bf16* __restrict__ x,
                                               const float* __restrict__ g,
                                               bf16* __restrict__ out)
{
  int row = blockIdx.x * 4 + (threadIdx.x >> 6);
  int lane = threadIdx.x & 63;
  bf16x8 v = *(const bf16x8*)(x + (long)row * 512 + lane * 8);
  float f[8];
#pragma unroll
  for (int i = 0; i < 8; i++) f[i] = (float)v[i];
  float s = ((f[0] + f[1]) + (f[2] + f[3])) + ((f[4] + f[5]) + (f[6] + f[7]));
  float q = ((f[0]*f[0] + f[1]*f[1]) + (f[2]*f[2] + f[3]*f[3]))
          + ((f[4]*f[4] + f[5]*f[5]) + (f[6]*f[6] + f[7]*f[7]));
#pragma unroll
  for (int off = 32; off; off >>= 1) {
    s += __shfl_xor(s, off);
    q += __shfl_xor(q, off);
  }
  float mean = s * (1.f / 512.f);
  float var  = q * (1.f / 512.f) - mean * mean;
  float rs = rsqrtf(var + 1e-5f);
  f32x4 ga = *(const f32x4*)(g + lane * 8);
  f32x4 gb = *(const f32x4*)(g + lane * 8 + 4);
  bf16x8 r;
#pragma unroll
  for (int i = 0; i < 4; i++) r[i] = (bf16)((f[i] - mean) * rs * ga[i]);
#pragma unroll
  for (int i = 0; i < 4; i++) r[4 + i] = (bf16)((f[4 + i] - mean) * rs * gb[i]);
  *(bf16x8*)(out + (long)row * 512 + lane * 8) = r;
}

// ---------------------------------------------------------------------------
// Fused GEGLU dual-GEMM v4 (3-buf depth-2, swizzled — rounds 19/20)
// ---------------------------------------------------------------------------
__global__ __launch_bounds__(256) void gemm_geglu(
    const bf16* __restrict__ A,
    const bf16* __restrict__ WH, const bf16* __restrict__ WG,
    const float* __restrict__ bH, const float* __restrict__ bG,
    bf16* __restrict__ D, int K)
{
  __shared__ bf16 As[3][128 * 32];
  __shared__ bf16 Hs[3][64 * 32];
  __shared__ bf16 Gs[3][64 * 32];
  const int tid = threadIdx.x;
  const int lane = tid & 63;
  const int wave = tid >> 6;
  const int l15 = lane & 15, lg = lane >> 4;
  const int wm = (wave & 1) << 6;
  const int wn = (wave >> 1) << 5;

  int bx, by;
  xcd_map(blockIdx.y * gridDim.x + blockIdx.x, gridDim.x * gridDim.y,
          gridDim.y, bx, by);

  const bf16* Ab = A + (long)(bx * 128) * K;
  const bf16* Hb = WH + (long)(by * 64) * K;
  const bf16* Gb = WG + (long)(by * 64) * K;

  const int srow = lane >> 2;
  const int schunk = (((lane & 3) ^ ((lane >> 3) & 3))) * 8;  // swizzled source
  const bf16* gA = Ab + (long)(wave * 32 + srow) * K + schunk;
  const bf16* gH = Hb + (long)(wave * 16 + srow) * K + schunk;
  const bf16* gG = Gb + (long)(wave * 16 + srow) * K + schunk;
  const int lAoff = wave * 1024, lBoff = wave * 512;

  const int rc = (lg ^ ((l15 >> 1) & 3)) * 8;                 // swizzled read

  f32x4 aH[4][2] = {}, aG[4][2] = {};

  auto STAGE = [&](int buf, int t) {
    int k0 = t << 5;
    glds16(gA + k0, &As[buf][lAoff]);
    glds16(gA + 16 * K + k0, &As[buf][lAoff + 512]);
    glds16(gH + k0, &Hs[buf][lBoff]);
    glds16(gG + k0, &Gs[buf][lBoff]);
  };

  const int nt = K >> 5;
  STAGE(0, 0);
  STAGE(1, 1);

  int cur = 0;
  for (int t = 0; t < nt; ++t) {
    if (t + 2 < nt) {
      int sb = cur + 2; if (sb >= 3) sb -= 3;
      STAGE(sb, t + 2);
      asm volatile("s_waitcnt vmcnt(8)" ::: "memory");
    } else if (t + 2 == nt) {
      asm volatile("s_waitcnt vmcnt(4)" ::: "memory");
    } else {
      asm volatile("s_waitcnt vmcnt(0)" ::: "memory");
    }
    __builtin_amdgcn_s_barrier();
    __builtin_amdgcn_sched_barrier(0);

    bf16x8 af[4], hf[2], gf[2];
#pragma unroll
    for (int i = 0; i < 4; i++)
      af[i] = *(const bf16x8*)(&As[cur][(wm + i * 16 + l15) * 32 + rc]);
#pragma unroll
    for (int i = 0; i < 2; i++) {
      hf[i] = *(const bf16x8*)(&Hs[cur][(wn + i * 16 + l15) * 32 + rc]);
      gf[i] = *(const bf16x8*)(&Gs[cur][(wn + i * 16 + l15) * 32 + rc]);
    }
    __builtin_amdgcn_s_setprio(1);
#pragma unroll
    for (int mi = 0; mi < 4; mi++)
#pragma unroll
      for (int ni = 0; ni < 2; ni++) {
        aH[mi][ni] = __builtin_amdgcn_mfma_f32_16x16x32_bf16(af[mi], hf[ni],
                                                             aH[mi][ni], 0, 0, 0);
        aG[mi][ni] = __builtin_amdgcn_mfma_f32_16x16x32_bf16(af[mi], gf[ni],
                                                             aG[mi][ni], 0, 0, 0);
      }
    __builtin_amdgcn_s_setprio(0);
    asm volatile("s_waitcnt lgkmcnt(0)" ::: "memory");
    __builtin_amdgcn_sched_barrier(0);
    __builtin_amdgcn_s_barrier();
    cur = (cur == 2) ? 0 : cur + 1;
  }

  const int gr0 = bx * 128 + wm;
  const int gc0 = by * 64 + wn;
#pragma unroll
  for (int ni = 0; ni < 2; ni++) {
    int gc = gc0 + ni * 16 + l15;
    float bh = bH[gc], bg = bG[gc];
#pragma unroll
    for (int mi = 0; mi < 4; mi++) {
#pragma unroll
      for (int rr = 0; rr < 4; rr++) {
        int gr = gr0 + mi * 16 + 4 * lg + rr;
        float hv = aH[mi][ni][rr] + bh;
        float gv = aG[mi][ni][rr] + bg;
        float ge = 0.5f * gv * (1.f + erff(gv * 0.70710678118654752f));
        D[(long)gr * 2048 + gc] = (bf16)(hv * ge);
      }
    }
  }
}

// ---------------------------------------------------------------------------
// Flash attention v9 (round-16): no-max softmax, 4 waves, two KV tiles/window
// ---------------------------------------------------------------------------
__global__ __launch_bounds__(256) void flash_attn(
    const bf16* __restrict__ Q, int ldq,
    const bf16* __restrict__ Kt, int ldk,
    const bf16* __restrict__ V,
    bf16* __restrict__ O,
    int Nq, int Nkv)
{
  int wid = xcd_swz_local(blockIdx.y * gridDim.x + blockIdx.x,
                          gridDim.x * gridDim.y);
  const int i0 = (wid % gridDim.x) * 128;
  const int bh = wid / gridDim.x;
  const int b = bh >> 3, h = bh & 7;
  const int lane = threadIdx.x & 63, wave = threadIdx.x >> 6;
  const int l31 = lane & 31, hi = lane >> 5;

  __shared__ bf16 Ks[4][64 * 64];
  __shared__ bf16 Vs[4][64 * 64];

  const bf16* Qb = Q + ((long)b * Nq + i0 + wave * 32) * ldq + h * 64;
  const bf16* Kb = Kt + (long)b * Nkv * ldk + h * 64;
  const bf16* Vb = V + ((long)b * 512 + h * 64) * Nkv;
  bf16* Ob = O + ((long)b * Nq + i0 + wave * 32) * 512 + h * 64;

  const float QSC = 0.125f * 1.44269504f;
  bf16x8 qf[4];
#pragma unroll
  for (int ds = 0; ds < 4; ds++) {
    qf[ds] = *(const bf16x8*)(Qb + (long)l31 * ldq + ds * 16 + 8 * hi);
#pragma unroll
    for (int e = 0; e < 8; e++) qf[ds][e] = (bf16)((float)qf[ds][e] * QSC);
  }

  const int srow = lane >> 3;
  const int schk = ((lane & 7) ^ srow) * 8;
  const int r0 = wave * 16;

  const int nt = Nkv >> 6;
  const int np = nt >> 1;

  auto STAGE = [&](int buf, long j) {
    glds16(Kb + (j + r0 + srow) * ldk + schk, &Ks[buf][r0 * 64]);
    glds16(Kb + (j + r0 + 8 + srow) * ldk + schk, &Ks[buf][(r0 + 8) * 64]);
    glds16(Vb + (long)(r0 + srow) * Nkv + j + schk, &Vs[buf][r0 * 64]);
    glds16(Vb + (long)(r0 + 8 + srow) * Nkv + j + schk, &Vs[buf][(r0 + 8) * 64]);
  };

  f32x16 ot0 = {}, ot1 = {};
  float lrun = 0.f;

  auto QK = [&](f32x16& s0, f32x16& s1, int buf) {
    s0 = (f32x16){}; s1 = (f32x16){};
    __builtin_amdgcn_s_setprio(1);
#pragma unroll
    for (int ds = 0; ds < 4; ds++) {
      int ch = 2 * ds + hi;
      bf16x8 k0 = *(const bf16x8*)(&Ks[buf][l31 * 64 + ((ch ^ (l31 & 7)) * 8)]);
      bf16x8 k1 = *(const bf16x8*)(&Ks[buf][(32 + l31) * 64 + ((ch ^ (l31 & 7)) * 8)]);
      s0 = __builtin_amdgcn_mfma_f32_32x32x16_bf16(k0, qf[ds], s0, 0, 0, 0);
      s1 = __builtin_amdgcn_mfma_f32_32x32x16_bf16(k1, qf[ds], s1, 0, 0, 0);
    }
    __builtin_amdgcn_s_setprio(0);
  };

  auto SMPV = [&](f32x16& st0, f32x16& st1, int buf) {
    float sm[8];
#pragma unroll
    for (int r = 0; r < 16; r++) {
      st0[r] = fexp2(st0[r]);
      st1[r] = fexp2(st1[r]);
    }
#pragma unroll
    for (int r = 0; r < 8; r++)
      sm[r] = (st0[r] + st0[r + 8]) + (st1[r] + st1[r + 8]);
#pragma unroll
    for (int off = 4; off; off >>= 1)
#pragma unroll
      for (int r = 0; r < off; r++) sm[r] += sm[r + off];
    { float2 pr = swap_halves(sm[0]); lrun += pr.x + pr.y; }

    __builtin_amdgcn_s_setprio(1);
#pragma unroll
    for (int c = 0; c < 4; c++) {
      const f32x16& sv = (c < 2) ? st0 : st1;
      const int base = (c & 1) * 8;
      unsigned a0 = pk_bf16(sv[base + 0], sv[base + 1]);
      unsigned b0 = pk_bf16(sv[base + 4], sv[base + 5]);
      unsigned a1 = pk_bf16(sv[base + 2], sv[base + 3]);
      unsigned b1 = pk_bf16(sv[base + 6], sv[base + 7]);
      plswap(a0, b0);
      plswap(a1, b1);
      uint4 wd = make_uint4(a0, a1, b0, b1);
      bf16x8 pB = *(bf16x8*)&wd;
      int ch = 2 * c + hi;
#pragma unroll
      for (int dt = 0; dt < 2; dt++) {
        int r = dt * 32 + l31;
        bf16x8 vf = *(const bf16x8*)(&Vs[buf][r * 64 + ((ch ^ (l31 & 7)) * 8)]);
        if (dt == 0) ot0 = __builtin_amdgcn_mfma_f32_32x32x16_bf16(vf, pB, ot0, 0, 0, 0);
        else         ot1 = __builtin_amdgcn_mfma_f32_32x32x16_bf16(vf, pB, ot1, 0, 0, 0);
      }
    }
    __builtin_amdgcn_s_setprio(0);
  };

  STAGE(0, 0);
  STAGE(1, 64);

  for (int p = 0; p < np; ++p) {
    const int t0 = 2 * p;
    if (p + 1 < np) {
      STAGE((t0 + 2) & 3, (long)(t0 + 2) * 64);
      STAGE((t0 + 3) & 3, (long)(t0 + 3) * 64);
      asm volatile("s_waitcnt vmcnt(8)");
    } else {
      asm volatile("s_waitcnt vmcnt(0)");
    }
    __builtin_amdgcn_s_barrier();
    __builtin_amdgcn_sched_barrier(0);

    f32x16 sA0, sA1, sB0, sB1;
    QK(sA0, sA1, t0 & 3);
    QK(sB0, sB1, (t0 + 1) & 3);
    SMPV(sA0, sA1, t0 & 3);
    SMPV(sB0, sB1, (t0 + 1) & 3);

    asm volatile("s_waitcnt lgkmcnt(0)");
    __builtin_amdgcn_s_barrier();
  }

  __syncthreads();
  bf16* Ow = &Ks[0][0] + wave * 2048;
  float inv = 1.0f / lrun;
#pragma unroll
  for (int dt = 0; dt < 2; dt++) {
#pragma unroll
    for (int r = 0; r < 16; r++) {
      int d = dt * 32 + (r & 3) + 8 * (r >> 2) + 4 * hi;
      float v = (dt == 0 ? ot0[r] : ot1[r]) * inv;
      Ow[l31 * 64 + (((d >> 3) ^ (l31 & 7)) * 8) + (d & 7)] = (bf16)v;
    }
  }
  __syncthreads();
#pragma unroll
  for (int i = 0; i < 4; i++) {
    int ch = hi * 4 + i;
    uint4 wd = *(const uint4*)(&Ow[l31 * 64 + ((ch ^ (l31 & 7)) * 8)]);
    *(uint4*)(Ob + (long)l31 * 512 + ch * 8) = wd;
  }
}

// ---------------------------------------------------------------------------
// host
// ---------------------------------------------------------------------------
template <int BN>
static void launch_gemm(const bf16* A, long sAz, const bf16* B, long sBz,
                        int M, int N, int K, void* D, long sDz, int ldd,
                        const float* bias, const bf16* resid,
                        int mode, hipStream_t stream)
{
  gemm_nt<BN><<<dim3(M / 128, N / BN), dim3(256), 0, stream>>>(
      A, sAz, B, sBz, M, N, K, D, sDz, ldd, bias, resid, mode);
}

extern "C" void kernel_launch(void* const* d_in, const int* in_sizes, int n_in,
                              void* d_out, int out_size, void* d_ws, size_t ws_size,
                              hipStream_t stream)
{
  (void)in_sizes; (void)n_in; (void)out_size; (void)ws_size;
  const float* x     = (const float*)d_in[0];
  const float* ctx   = (const float*)d_in[1];
  const float* g1    = (const float*)d_in[2];
  const float* Wq1f  = (const float*)d_in[3];
  const float* Wk1f  = (const float*)d_in[4];
  const float* Wv1f  = (const float*)d_in[5];
  const float* Wo1f  = (const float*)d_in[6];
  const float* bo1   = (const float*)d_in[7];
  const float* g2    = (const float*)d_in[8];
  const float* Wq2f  = (const float*)d_in[9];
  const float* Wk2f  = (const float*)d_in[10];
  const float* Wv2f  = (const float*)d_in[11];
  const float* Wo2f  = (const float*)d_in[12];
  const float* bo2   = (const float*)d_in[13];
  const float* g3    = (const float*)d_in[14];
  const float* Wff1f = (const float*)d_in[15];
  const float* bff1  = (const float*)d_in[16];
  const float* Wff2f = (const float*)d_in[17];
  const float* bff2  = (const float*)d_in[18];

  char* wsp = (char*)d_ws;
  size_t off = 0;
  auto alloc = [&](size_t bytes) -> void* {
    void* p = wsp + off;
    off += (bytes + 255) & ~(size_t)255;
    return p;
  };

  bf16* xt    = (bf16*)alloc((size_t)8192 * 512 * 2);   // residual stream bf16
  bf16* x2    = (bf16*)alloc((size_t)8192 * 512 * 2);
  bf16* h     = (bf16*)alloc((size_t)8192 * 512 * 2);
  bf16* qkb   = (bf16*)alloc((size_t)8192 * 1024 * 2);
  bf16* qb    = (bf16*)alloc((size_t)8192 * 512 * 2);
  bf16* kb    = (bf16*)alloc((size_t)1024 * 512 * 2);
  bf16* vb    = (bf16*)alloc((size_t)8192 * 512 * 2);
  bf16* vb2   = (bf16*)alloc((size_t)1024 * 512 * 2);
  bf16* ao    = (bf16*)alloc((size_t)8192 * 512 * 2);
  bf16* ctxt  = (bf16*)alloc((size_t)1024 * 768 * 2);
  bf16* actb  = (bf16*)alloc((size_t)8192 * 2048 * 2);
  bf16* wqk1  = (bf16*)alloc((size_t)524288 * 2);
  bf16* wv1   = (bf16*)alloc((size_t)262144 * 2);
  bf16* wo1   = (bf16*)alloc((size_t)262144 * 2);
  bf16* wq2   = (bf16*)alloc((size_t)262144 * 2);
  bf16* wk2   = (bf16*)alloc((size_t)393216 * 2);
  bf16* wv2   = (bf16*)alloc((size_t)393216 * 2);
  bf16* wo2   = (bf16*)alloc((size_t)262144 * 2);
  bf16* wff1  = (bf16*)alloc((size_t)2097152 * 2);
  bf16* wff2  = (bf16*)alloc((size_t)1048576 * 2);

  {
    CvtPack p;
    const float* s[10] = {Wq1f, Wk1f, Wv1f, Wo1f, Wq2f, Wk2f, Wv2f, Wo2f, Wff1f, Wff2f};
    bf16* d[10] = {wqk1, wqk1 + 262144, wv1, wo1, wq2, wk2, wv2, wo2, wff1, wff2};
    int n[10] = {262144, 262144, 262144, 262144, 262144, 393216, 393216, 262144,
                 2097152, 1048576};
    int cum = 0;
    for (int i = 0; i < 10; i++) {
      p.src[i] = s[i]; p.dst[i] = d[i];
      cum += n[i] / 4; p.end4[i] = cum;
    }
    prologue<<<dim3(10240), dim3(256), 0, stream>>>(p, cum, x, xt, ctx, ctxt);
  }

  // ---- block 1: self attention (+ hoisted cross K/V) ----
  ln_rows<<<dim3(2048), dim3(256), 0, stream>>>(xt, g1, h);
  gemm_uber<<<dim3(1152), dim3(256), 0, stream>>>(
      h, wqk1, qkb, wv1, vb, ctxt, wk2, kb, wv2, vb2);
  flash_attn<<<dim3(16, 32), dim3(256), 0, stream>>>(qkb, 1024, qkb + 512, 1024,
                                                     vb, ao, 2048, 2048);
  launch_gemm<64>(ao, 0, wo1, 0, 8192, 512, 512, x2, 0, 512,
                  bo1, xt, 2, stream);

  // ---- block 2: cross attention ----
  ln_rows<<<dim3(2048), dim3(256), 0, stream>>>(x2, g2, h);
  launch_gemm<64>(h, 0, wq2, 0, 8192, 512, 512, qb, 0, 512,
                  nullptr, nullptr, 0, stream);
  flash_attn<<<dim3(16, 32), dim3(256), 0, stream>>>(qb, 512, kb, 512,
                                                     vb2, ao, 2048, 256);
  launch_gemm<64>(ao, 0, wo2, 0, 8192, 512, 512, x2, 0, 512,
                  bo2, x2, 2, stream);

  // ---- block 3: GEGLU FF; ff2 stores transposed directly to d_out ----
  ln_rows<<<dim3(2048), dim3(256), 0, stream>>>(x2, g3, h);
  gemm_geglu<<<dim3(64, 32), dim3(256), 0, stream>>>(
      h, wff1, wff1 + (long)2048 * 512, bff1, bff1 + 2048, actb, 512);
  launch_gemm<64>(actb, 0, wff2, 0, 8192, 512, 2048, d_out, 0, 512,
                  bff2, x2, 3, stream);
}

// Round 27
// 242.900 us; speedup vs baseline: 1.0052x; 1.0022x over previous
//
#include <hip/hip_runtime.h>
#include <hip/hip_bf16.h>

typedef __bf16 bf16;
typedef __attribute__((ext_vector_type(8))) __bf16 bf16x8;
typedef __attribute__((ext_vector_type(4))) __bf16 bf16x4;
typedef __attribute__((ext_vector_type(4))) float f32x4;
typedef __attribute__((ext_vector_type(16))) float f32x16;

// async global->LDS: stages 16B per lane; LDS dest = uniform base + lane*16
__device__ __forceinline__ void glds16(const bf16* g, bf16* l)
{
  __builtin_amdgcn_global_load_lds(
      (const __attribute__((address_space(1))) unsigned int*)g,
      (__attribute__((address_space(3))) unsigned int*)l, 16, 0, 0);
}

__device__ __forceinline__ unsigned pk_bf16(float lo, float hi)
{
  unsigned r;
  asm("v_cvt_pk_bf16_f32 %0, %1, %2" : "=v"(r) : "v"(lo), "v"(hi));
  return r;
}
__device__ __forceinline__ void plswap(unsigned& a, unsigned& b)
{
  asm volatile("v_permlane32_swap_b32 %0, %1" : "+v"(a), "+v"(b));
}
__device__ __forceinline__ float2 swap_halves(float x)
{
  unsigned a = __float_as_uint(x), b = a;
  plswap(a, b);
  return make_float2(__uint_as_float(a), __uint_as_float(b));
}
// raw v_exp_f32: 2^x, single instruction (exp2f() libcall was +15us, round 7)
__device__ __forceinline__ float fexp2(float x)
{
  float r;
  asm("v_exp_f32 %0, %1" : "=v"(r) : "v"(x));
  return r;
}

// bijective XCD-chunked remap (m204) of a LOCAL flat id over nwg workgroups.
__device__ __forceinline__ int xcd_swz_local(int bid, int nwg)
{
  int q = nwg >> 3, r = nwg & 7;
  int xcd = bid & 7, idx = bid >> 3;
  return (xcd < r) ? (xcd * (q + 1) + idx) : (r * (q + 1) + (xcd - r) * q + idx);
}

// XCD chunk mapping with bx FAST-VARYING inside the chunk (round-17: geglu
// FETCH 70->20.7MB). Requires nwg%8==0 and (nwg/8)%gy==0 (true for all grids).
__device__ __forceinline__ void xcd_map(int bid, int nwg, int gy,
                                        int& bx, int& by)
{
  int q = nwg >> 3;
  int xcd = bid & 7, idx = bid >> 3;
  int stripe = q / gy;
  bx = xcd * stripe + idx % stripe;
  by = idx / stripe;
}

// ---------------------------------------------------------------------------
// Round-20 LDS swizzle (verified: SQ_LDS_BANK_CONFLICT 4.19M -> 0):
//   stage source chunk ^= (lane>>3)&3 ; ds_read chunk ^= (l15>>1)&3
// Round-27: geglu -> 2-buf depth-1 (32KB, 5 blk/CU) — occupancy-axis extreme.
// ---------------------------------------------------------------------------

// ---------------------------------------------------------------------------
// GEMM device body (4-buf, two K-tiles per barrier window) — round-20 proven.
// modes: 0 bf16(+bias); 2 bf16(acc+bias+resid); 3 = f32 acc+bias+resid
//        stored TRANSPOSED to d_out[b][c][n].
// ---------------------------------------------------------------------------
template <int BN>
__device__ __forceinline__ void gemm_dev(
    bf16* AsL, bf16* BsL,                 // 4 bufs: 128*32 and BN*32 each
    int bx, int by, long z,
    const bf16* __restrict__ A, long sAz,
    const bf16* __restrict__ B, long sBz,
    int M, int N, int K,
    void* __restrict__ Dp, long sDz, int ldd,
    const float* __restrict__ bias,
    const bf16* __restrict__ resid,
    int mode)
{
  constexpr int NI = BN / 32;
  const int tid = threadIdx.x;
  const int lane = tid & 63;
  const int wave = tid >> 6;
  const int l15 = lane & 15, lg = lane >> 4;
  const int wm = (wave & 1) << 6;
  const int wn = (BN == 128) ? ((wave >> 1) << 6) : ((wave >> 1) << 5);

  const bf16* Ab = A + z * sAz + (long)(bx * 128) * K;
  const bf16* Bb = B + z * sBz + (long)(by * BN) * K;

  const int srow = lane >> 2;
  const int schunk = (((lane & 3) ^ ((lane >> 3) & 3))) * 8;  // swizzled source
  const bf16* gA = Ab + (long)(wave * 32 + srow) * K + schunk;
  const int lAoff = wave * 1024;
  const bf16* gB;
  int lBoff;
  if (BN == 128) { gB = Bb + (long)(wave * 32 + srow) * K + schunk; lBoff = wave * 1024; }
  else           { gB = Bb + (long)(wave * 16 + srow) * K + schunk; lBoff = wave * 512; }

  const int rc = (lg ^ ((l15 >> 1) & 3)) * 8;                 // swizzled read

  f32x4 acc[4][NI] = {};

  auto STAGE = [&](int t) {
    int buf = t & 3;
    int k0 = t << 5;
    glds16(gA + k0, AsL + buf * 4096 + lAoff);
    glds16(gA + 16 * K + k0, AsL + buf * 4096 + lAoff + 512);
    glds16(gB + k0, BsL + buf * (BN * 32) + lBoff);
    if (BN == 128) glds16(gB + 16 * K + k0, BsL + buf * (BN * 32) + lBoff + 512);
  };

  auto COMPUTE = [&](int t) {
    int buf = t & 3;
    bf16x8 af[4], bfr[NI];
#pragma unroll
    for (int i = 0; i < 4; i++)
      af[i] = *(const bf16x8*)(AsL + buf * 4096 + (wm + i * 16 + l15) * 32 + rc);
#pragma unroll
    for (int i = 0; i < NI; i++)
      bfr[i] = *(const bf16x8*)(BsL + buf * (BN * 32) + (wn + i * 16 + l15) * 32 + rc);
    __builtin_amdgcn_s_setprio(1);
#pragma unroll
    for (int mi = 0; mi < 4; mi++)
#pragma unroll
      for (int ni = 0; ni < NI; ni++)
        acc[mi][ni] = __builtin_amdgcn_mfma_f32_16x16x32_bf16(af[mi], bfr[ni],
                                                              acc[mi][ni], 0, 0, 0);
    __builtin_amdgcn_s_setprio(0);
  };

  const int nt = K >> 5;          // even for all K used (512/768/2048)
  const int np = nt >> 1;
  STAGE(0);
  STAGE(1);

  for (int p = 0; p < np; ++p) {
    const int t0 = 2 * p;
    if (p + 1 < np) {
      STAGE(t0 + 2);
      STAGE(t0 + 3);
      if constexpr (BN == 128) asm volatile("s_waitcnt vmcnt(8)" ::: "memory");
      else                     asm volatile("s_waitcnt vmcnt(6)" ::: "memory");
    } else {
      asm volatile("s_waitcnt vmcnt(0)" ::: "memory");
    }
    __builtin_amdgcn_s_barrier();
    __builtin_amdgcn_sched_barrier(0);

    COMPUTE(t0);
    COMPUTE(t0 + 1);

    asm volatile("s_waitcnt lgkmcnt(0)" ::: "memory");
    __builtin_amdgcn_sched_barrier(0);
    __builtin_amdgcn_s_barrier();
  }

  const int gr0 = bx * 128 + wm;
  const int gc0 = by * BN + wn;

  if (mode != 3) {
#pragma unroll
    for (int ni = 0; ni < NI; ni++) {
      int gc = gc0 + ni * 16 + l15;
      float bv = bias ? bias[gc] : 0.f;
#pragma unroll
      for (int mi = 0; mi < 4; mi++) {
#pragma unroll
        for (int rr = 0; rr < 4; rr++) {
          int gr = gr0 + mi * 16 + 4 * lg + rr;
          long o = z * sDz + (long)gr * ldd + gc;
          float val = acc[mi][ni][rr] + bv;
          if (mode == 0) ((bf16*)Dp)[o] = (bf16)val;
          else           ((bf16*)Dp)[o] = (bf16)(val + (float)resid[o]);
        }
      }
    }
  } else {
    // transposed store: d_out[b][c][n] = acc + bias + resid (BN==64 path)
    float* T = (float*)AsL;                    // 64 x 68 f32 tile
    const int bb = (bx * 128) >> 11;
    const int n0 = (bx * 128) & 2047;
    float* dout = (float*)Dp;
#pragma unroll
    for (int half = 0; half < 2; half++) {
      if ((wave & 1) == half) {
#pragma unroll
        for (int ni = 0; ni < NI; ni++) {
          int cl = wn + ni * 16 + l15;
          float bv = bias ? bias[by * BN + cl] : 0.f;
#pragma unroll
          for (int mi = 0; mi < 4; mi++) {
#pragma unroll
            for (int rr = 0; rr < 4; rr++) {
              int nl = mi * 16 + 4 * lg + rr;
              int gr = gr0 + mi * 16 + 4 * lg + rr;
              float val = acc[mi][ni][rr] + bv
                        + (float)resid[(long)gr * ldd + by * BN + cl];
              T[cl * 68 + nl] = val;
            }
          }
        }
      }
      __syncthreads();
      {
        int c = tid >> 2, seg = tid & 3;
        long ob = (long)bb * 512 * 2048 + (long)(by * BN + c) * 2048
                + n0 + half * 64 + seg * 16;
#pragma unroll
        for (int j = 0; j < 4; j++) {
          float4 v = *(float4*)&T[c * 68 + seg * 16 + j * 4];
          *(float4*)(dout + ob + j * 4) = v;
        }
      }
      __syncthreads();
    }
  }
}

// standalone GEMM kernel (512-block grids: grid-limited 2/CU, pairing free)
template <int BN>
__global__ __launch_bounds__(256) void gemm_nt(
    const bf16* __restrict__ A, long sAz,
    const bf16* __restrict__ B, long sBz,
    int M, int N, int K,
    void* __restrict__ Dp, long sDz, int ldd,
    const float* __restrict__ bias,
    const bf16* __restrict__ resid,
    int mode)
{
  __shared__ bf16 As[4 * 128 * 32];
  __shared__ bf16 Bs[4 * BN * 32];
  int bx, by;
  xcd_map(blockIdx.y * gridDim.x + blockIdx.x, gridDim.x * gridDim.y,
          gridDim.y, bx, by);
  gemm_dev<BN>(As, Bs, bx, by, 0, A, sAz, B, sBz, M, N, K,
               Dp, sDz, ldd, bias, resid, mode);
}

// ---------------------------------------------------------------------------
// uber GEMM: qk | wv1 | kb | wv2 (round-20 4-buf bodies)
// ---------------------------------------------------------------------------
__global__ __launch_bounds__(256) void gemm_uber(
    const bf16* __restrict__ h,  const bf16* __restrict__ wqk1, bf16* qkb,
    const bf16* __restrict__ wv1w, bf16* vb,
    const bf16* __restrict__ ctxt, const bf16* __restrict__ wk2w, bf16* kb,
    const bf16* __restrict__ wv2w, bf16* vb2)
{
  __shared__ bf16 As[4 * 128 * 32];
  __shared__ bf16 Bs[4 * 128 * 32];
  int gid = blockIdx.x;
  if (gid < 512) {
    int bx, by;
    xcd_map(gid, 512, 8, bx, by);
    gemm_dev<128>(As, Bs, bx, by, 0, h, 0, wqk1, 0,
                  8192, 1024, 512, qkb, 0, 1024, nullptr, nullptr, 0);
  } else if (gid < 1024) {
    int l = gid - 512;
    int z = l >> 7, r = l & 127;
    gemm_dev<64>(As, Bs, r & 3, r >> 2, z, wv1w, 0, h, (long)2048 * 512,
                 512, 2048, 512, vb, (long)512 * 2048, 2048,
                 nullptr, nullptr, 0);
  } else if (gid < 1088) {
    int bx, by;
    xcd_map(gid - 1024, 64, 8, bx, by);
    gemm_dev<64>(As, Bs, bx, by, 0, ctxt, 0, wk2w, 0,
                 1024, 512, 768, kb, 0, 512, nullptr, nullptr, 0);
  } else {
    int l = gid - 1088;
    int z = l >> 4, r = l & 15;
    gemm_dev<64>(As, Bs, r & 3, r >> 2, z, wv2w, 0, ctxt, (long)256 * 768,
                 512, 256, 768, vb2, (long)512 * 256, 256,
                 nullptr, nullptr, 0);
  }
}

// ---------------------------------------------------------------------------
// prologue: weight cvt (10 segs) + x transpose (bf16 out) + ctx transpose
// ---------------------------------------------------------------------------
struct CvtPack {
  const float* src[10];
  bf16* dst[10];
  int end4[10];
};

__global__ __launch_bounds__(256) void prologue(
    CvtPack p, int total4,
    const float* __restrict__ x, bf16* __restrict__ xt,
    const float* __restrict__ ctx, bf16* __restrict__ ctxt)
{
  __shared__ float tile[32][33];
  int gid = blockIdx.x;
  const int CVT_B = 5376;
  if (gid < CVT_B) {
    int i = gid * 256 + threadIdx.x;
    if (i >= total4) return;
    int s = 0;
#pragma unroll
    for (int k = 0; k < 9; k++) s += (i >= p.end4[k]) ? 1 : 0;
    int base = s ? p.end4[s - 1] : 0;
    long j = (long)(i - base) * 4;
    f32x4 v = *(const f32x4*)(p.src[s] + j);
    bf16x4 r;
    r.x = (bf16)v.x; r.y = (bf16)v.y; r.z = (bf16)v.z; r.w = (bf16)v.w;
    *(bf16x4*)(p.dst[s] + j) = r;
  } else if (gid < CVT_B + 4096) {
    int l = gid - CVT_B;
    int bxx = l & 63, byy = (l >> 6) & 15, bz = l >> 10;
    const float* in = x + (long)bz * 512 * 2048;
    bf16* out = xt + (long)bz * 512 * 2048;
    int c0 = bxx * 32, r0 = byy * 32;
    int tx = threadIdx.x & 31, ty = threadIdx.x >> 5;
    for (int i = ty; i < 32; i += 8)
      tile[i][tx] = in[(long)(r0 + i) * 2048 + c0 + tx];
    __syncthreads();
    for (int i = ty; i < 32; i += 8)
      out[(long)(c0 + i) * 512 + r0 + tx] = (bf16)tile[tx][i];
  } else {
    int l = gid - CVT_B - 4096;
    int bxx = l & 7, byy = (l >> 3) % 24, bz = l / 192;
    const float* in = ctx + (long)bz * 768 * 256;
    bf16* out = ctxt + (long)bz * 768 * 256;
    int c0 = bxx * 32, r0 = byy * 32;
    int tx = threadIdx.x & 31, ty = threadIdx.x >> 5;
    for (int i = ty; i < 32; i += 8)
      tile[i][tx] = in[(long)(r0 + i) * 256 + c0 + tx];
    __syncthreads();
    for (int i = ty; i < 32; i += 8)
      out[(long)(c0 + i) * 768 + r0 + tx] = (bf16)tile[tx][i];
  }
}

// ---------------------------------------------------------------------------
// LayerNorm rows of 512, bf16 in (vectorized bf16x8), bf16 out; 1 wave/row
// ---------------------------------------------------------------------------
__global__ __launch_bounds__(256) void ln_rows(const bf16* __restrict__ x,
                                               const float* __restrict__ g,
                                               bf16* __restrict__ out)
{
  int row = blockIdx.x * 4 + (threadIdx.x >> 6);
  int lane = threadIdx.x & 63;
  bf16x8 v = *(const bf16x8*)(x + (long)row * 512 + lane * 8);
  float f[8];
#pragma unroll
  for (int i = 0; i < 8; i++) f[i] = (float)v[i];
  float s = ((f[0] + f[1]) + (f[2] + f[3])) + ((f[4] + f[5]) + (f[6] + f[7]));
  float q = ((f[0]*f[0] + f[1]*f[1]) + (f[2]*f[2] + f[3]*f[3]))
          + ((f[4]*f[4] + f[5]*f[5]) + (f[6]*f[6] + f[7]*f[7]));
#pragma unroll
  for (int off = 32; off; off >>= 1) {
    s += __shfl_xor(s, off);
    q += __shfl_xor(q, off);
  }
  float mean = s * (1.f / 512.f);
  float var  = q * (1.f / 512.f) - mean * mean;
  float rs = rsqrtf(var + 1e-5f);
  f32x4 ga = *(const f32x4*)(g + lane * 8);
  f32x4 gb = *(const f32x4*)(g + lane * 8 + 4);
  bf16x8 r;
#pragma unroll
  for (int i = 0; i < 4; i++) r[i] = (bf16)((f[i] - mean) * rs * ga[i]);
#pragma unroll
  for (int i = 0; i < 4; i++) r[4 + i] = (bf16)((f[4 + i] - mean) * rs * gb[i]);
  *(bf16x8*)(out + (long)row * 512 + lane * 8) = r;
}

// ---------------------------------------------------------------------------
// Fused GEGLU dual-GEMM v6 (round 27): 2-buf depth-1, 32KB LDS -> 5 blk/CU.
// Occupancy-axis extreme (3>2>1 measured; 5 untested). Same swizzle/epilogue.
// ---------------------------------------------------------------------------
__global__ __launch_bounds__(256) void gemm_geglu(
    const bf16* __restrict__ A,
    const bf16* __restrict__ WH, const bf16* __restrict__ WG,
    const float* __restrict__ bH, const float* __restrict__ bG,
    bf16* __restrict__ D, int K)
{
  __shared__ bf16 As[2][128 * 32];
  __shared__ bf16 Hs[2][64 * 32];
  __shared__ bf16 Gs[2][64 * 32];
  const int tid = threadIdx.x;
  const int lane = tid & 63;
  const int wave = tid >> 6;
  const int l15 = lane & 15, lg = lane >> 4;
  const int wm = (wave & 1) << 6;
  const int wn = (wave >> 1) << 5;

  int bx, by;
  xcd_map(blockIdx.y * gridDim.x + blockIdx.x, gridDim.x * gridDim.y,
          gridDim.y, bx, by);

  const bf16* Ab = A + (long)(bx * 128) * K;
  const bf16* Hb = WH + (long)(by * 64) * K;
  const bf16* Gb = WG + (long)(by * 64) * K;

  const int srow = lane >> 2;
  const int schunk = (((lane & 3) ^ ((lane >> 3) & 3))) * 8;  // swizzled source
  const bf16* gA = Ab + (long)(wave * 32 + srow) * K + schunk;
  const bf16* gH = Hb + (long)(wave * 16 + srow) * K + schunk;
  const bf16* gG = Gb + (long)(wave * 16 + srow) * K + schunk;
  const int lAoff = wave * 1024, lBoff = wave * 512;

  const int rc = (lg ^ ((l15 >> 1) & 3)) * 8;                 // swizzled read

  f32x4 aH[4][2] = {}, aG[4][2] = {};

  auto STAGE = [&](int buf, int t) {
    int k0 = t << 5;
    glds16(gA + k0, &As[buf][lAoff]);
    glds16(gA + 16 * K + k0, &As[buf][lAoff + 512]);
    glds16(gH + k0, &Hs[buf][lBoff]);
    glds16(gG + k0, &Gs[buf][lBoff]);
  };

  const int nt = K >> 5;
  STAGE(0, 0);

  int cur = 0;
  for (int t = 0; t < nt; ++t) {
    // wait for tile t (this wave's 4 loads drained -> its LDS writes done),
    // then barrier so ALL waves' portions of buffer `cur` are visible.
    asm volatile("s_waitcnt vmcnt(0)" ::: "memory");
    __builtin_amdgcn_s_barrier();
    __builtin_amdgcn_sched_barrier(0);

    // issue next tile into the freed buffer (reads of it completed before
    // the previous window's closing barrier); lands during this compute.
    if (t + 1 < nt) STAGE(cur ^ 1, t + 1);

    bf16x8 af[4], hf[2], gf[2];
#pragma unroll
    for (int i = 0; i < 4; i++)
      af[i] = *(const bf16x8*)(&As[cur][(wm + i * 16 + l15) * 32 + rc]);
#pragma unroll
    for (int i = 0; i < 2; i++) {
      hf[i] = *(const bf16x8*)(&Hs[cur][(wn + i * 16 + l15) * 32 + rc]);
      gf[i] = *(const bf16x8*)(&Gs[cur][(wn + i * 16 + l15) * 32 + rc]);
    }
    __builtin_amdgcn_s_setprio(1);
#pragma unroll
    for (int mi = 0; mi < 4; mi++)
#pragma unroll
      for (int ni = 0; ni < 2; ni++) {
        aH[mi][ni] = __builtin_amdgcn_mfma_f32_16x16x32_bf16(af[mi], hf[ni],
                                                             aH[mi][ni], 0, 0, 0);
        aG[mi][ni] = __builtin_amdgcn_mfma_f32_16x16x32_bf16(af[mi], gf[ni],
                                                             aG[mi][ni], 0, 0, 0);
      }
    __builtin_amdgcn_s_setprio(0);
    asm volatile("s_waitcnt lgkmcnt(0)" ::: "memory");
    __builtin_amdgcn_sched_barrier(0);
    __builtin_amdgcn_s_barrier();
    cur ^= 1;
  }

  const int gr0 = bx * 128 + wm;
  const int gc0 = by * 64 + wn;
#pragma unroll
  for (int ni = 0; ni < 2; ni++) {
    int gc = gc0 + ni * 16 + l15;
    float bh = bH[gc], bg = bG[gc];
#pragma unroll
    for (int mi = 0; mi < 4; mi++) {
#pragma unroll
      for (int rr = 0; rr < 4; rr++) {
        int gr = gr0 + mi * 16 + 4 * lg + rr;
        float hv = aH[mi][ni][rr] + bh;
        float gv = aG[mi][ni][rr] + bg;
        float ge = 0.5f * gv * (1.f + erff(gv * 0.70710678118654752f));
        D[(long)gr * 2048 + gc] = (bf16)(hv * ge);
      }
    }
  }
}

// ---------------------------------------------------------------------------
// Flash attention v9 (round-16): no-max softmax, 4 waves, two KV tiles/window
// ---------------------------------------------------------------------------
__global__ __launch_bounds__(256) void flash_attn(
    const bf16* __restrict__ Q, int ldq,
    const bf16* __restrict__ Kt, int ldk,
    const bf16* __restrict__ V,
    bf16* __restrict__ O,
    int Nq, int Nkv)
{
  int wid = xcd_swz_local(blockIdx.y * gridDim.x + blockIdx.x,
                          gridDim.x * gridDim.y);
  const int i0 = (wid % gridDim.x) * 128;
  const int bh = wid / gridDim.x;
  const int b = bh >> 3, h = bh & 7;
  const int lane = threadIdx.x & 63, wave = threadIdx.x >> 6;
  const int l31 = lane & 31, hi = lane >> 5;

  __shared__ bf16 Ks[4][64 * 64];
  __shared__ bf16 Vs[4][64 * 64];

  const bf16* Qb = Q + ((long)b * Nq + i0 + wave * 32) * ldq + h * 64;
  const bf16* Kb = Kt + (long)b * Nkv * ldk + h * 64;
  const bf16* Vb = V + ((long)b * 512 + h * 64) * Nkv;
  bf16* Ob = O + ((long)b * Nq + i0 + wave * 32) * 512 + h * 64;

  const float QSC = 0.125f * 1.44269504f;
  bf16x8 qf[4];
#pragma unroll
  for (int ds = 0; ds < 4; ds++) {
    qf[ds] = *(const bf16x8*)(Qb + (long)l31 * ldq + ds * 16 + 8 * hi);
#pragma unroll
    for (int e = 0; e < 8; e++) qf[ds][e] = (bf16)((float)qf[ds][e] * QSC);
  }

  const int srow = lane >> 3;
  const int schk = ((lane & 7) ^ srow) * 8;
  const int r0 = wave * 16;

  const int nt = Nkv >> 6;
  const int np = nt >> 1;

  auto STAGE = [&](int buf, long j) {
    glds16(Kb + (j + r0 + srow) * ldk + schk, &Ks[buf][r0 * 64]);
    glds16(Kb + (j + r0 + 8 + srow) * ldk + schk, &Ks[buf][(r0 + 8) * 64]);
    glds16(Vb + (long)(r0 + srow) * Nkv + j + schk, &Vs[buf][r0 * 64]);
    glds16(Vb + (long)(r0 + 8 + srow) * Nkv + j + schk, &Vs[buf][(r0 + 8) * 64]);
  };

  f32x16 ot0 = {}, ot1 = {};
  float lrun = 0.f;

  auto QK = [&](f32x16& s0, f32x16& s1, int buf) {
    s0 = (f32x16){}; s1 = (f32x16){};
    __builtin_amdgcn_s_setprio(1);
#pragma unroll
    for (int ds = 0; ds < 4; ds++) {
      int ch = 2 * ds + hi;
      bf16x8 k0 = *(const bf16x8*)(&Ks[buf][l31 * 64 + ((ch ^ (l31 & 7)) * 8)]);
      bf16x8 k1 = *(const bf16x8*)(&Ks[buf][(32 + l31) * 64 + ((ch ^ (l31 & 7)) * 8)]);
      s0 = __builtin_amdgcn_mfma_f32_32x32x16_bf16(k0, qf[ds], s0, 0, 0, 0);
      s1 = __builtin_amdgcn_mfma_f32_32x32x16_bf16(k1, qf[ds], s1, 0, 0, 0);
    }
    __builtin_amdgcn_s_setprio(0);
  };

  auto SMPV = [&](f32x16& st0, f32x16& st1, int buf) {
    float sm[8];
#pragma unroll
    for (int r = 0; r < 16; r++) {
      st0[r] = fexp2(st0[r]);
      st1[r] = fexp2(st1[r]);
    }
#pragma unroll
    for (int r = 0; r < 8; r++)
      sm[r] = (st0[r] + st0[r + 8]) + (st1[r] + st1[r + 8]);
#pragma unroll
    for (int off = 4; off; off >>= 1)
#pragma unroll
      for (int r = 0; r < off; r++) sm[r] += sm[r + off];
    { float2 pr = swap_halves(sm[0]); lrun += pr.x + pr.y; }

    __builtin_amdgcn_s_setprio(1);
#pragma unroll
    for (int c = 0; c < 4; c++) {
      const f32x16& sv = (c < 2) ? st0 : st1;
      const int base = (c & 1) * 8;
      unsigned a0 = pk_bf16(sv[base + 0], sv[base + 1]);
      unsigned b0 = pk_bf16(sv[base + 4], sv[base + 5]);
      unsigned a1 = pk_bf16(sv[base + 2], sv[base + 3]);
      unsigned b1 = pk_bf16(sv[base + 6], sv[base + 7]);
      plswap(a0, b0);
      plswap(a1, b1);
      uint4 wd = make_uint4(a0, a1, b0, b1);
      bf16x8 pB = *(bf16x8*)&wd;
      int ch = 2 * c + hi;
#pragma unroll
      for (int dt = 0; dt < 2; dt++) {
        int r = dt * 32 + l31;
        bf16x8 vf = *(const bf16x8*)(&Vs[buf][r * 64 + ((ch ^ (l31 & 7)) * 8)]);
        if (dt == 0) ot0 = __builtin_amdgcn_mfma_f32_32x32x16_bf16(vf, pB, ot0, 0, 0, 0);
        else         ot1 = __builtin_amdgcn_mfma_f32_32x32x16_bf16(vf, pB, ot1, 0, 0, 0);
      }
    }
    __builtin_amdgcn_s_setprio(0);
  };

  STAGE(0, 0);
  STAGE(1, 64);

  for (int p = 0; p < np; ++p) {
    const int t0 = 2 * p;
    if (p + 1 < np) {
      STAGE((t0 + 2) & 3, (long)(t0 + 2) * 64);
      STAGE((t0 + 3) & 3, (long)(t0 + 3) * 64);
      asm volatile("s_waitcnt vmcnt(8)");
    } else {
      asm volatile("s_waitcnt vmcnt(0)");
    }
    __builtin_amdgcn_s_barrier();
    __builtin_amdgcn_sched_barrier(0);

    f32x16 sA0, sA1, sB0, sB1;
    QK(sA0, sA1, t0 & 3);
    QK(sB0, sB1, (t0 + 1) & 3);
    SMPV(sA0, sA1, t0 & 3);
    SMPV(sB0, sB1, (t0 + 1) & 3);

    asm volatile("s_waitcnt lgkmcnt(0)");
    __builtin_amdgcn_s_barrier();
  }

  __syncthreads();
  bf16* Ow = &Ks[0][0] + wave * 2048;
  float inv = 1.0f / lrun;
#pragma unroll
  for (int dt = 0; dt < 2; dt++) {
#pragma unroll
    for (int r = 0; r < 16; r++) {
      int d = dt * 32 + (r & 3) + 8 * (r >> 2) + 4 * hi;
      float v = (dt == 0 ? ot0[r] : ot1[r]) * inv;
      Ow[l31 * 64 + (((d >> 3) ^ (l31 & 7)) * 8) + (d & 7)] = (bf16)v;
    }
  }
  __syncthreads();
#pragma unroll
  for (int i = 0; i < 4; i++) {
    int ch = hi * 4 + i;
    uint4 wd = *(const uint4*)(&Ow[l31 * 64 + ((ch ^ (l31 & 7)) * 8)]);
    *(uint4*)(Ob + (long)l31 * 512 + ch * 8) = wd;
  }
}

// ---------------------------------------------------------------------------
// host
// ---------------------------------------------------------------------------
template <int BN>
static void launch_gemm(const bf16* A, long sAz, const bf16* B, long sBz,
                        int M, int N, int K, void* D, long sDz, int ldd,
                        const float* bias, const bf16* resid,
                        int mode, hipStream_t stream)
{
  gemm_nt<BN><<<dim3(M / 128, N / BN), dim3(256), 0, stream>>>(
      A, sAz, B, sBz, M, N, K, D, sDz, ldd, bias, resid, mode);
}

extern "C" void kernel_launch(void* const* d_in, const int* in_sizes, int n_in,
                              void* d_out, int out_size, void* d_ws, size_t ws_size,
                              hipStream_t stream)
{
  (void)in_sizes; (void)n_in; (void)out_size; (void)ws_size;
  const float* x     = (const float*)d_in[0];
  const float* ctx   = (const float*)d_in[1];
  const float* g1    = (const float*)d_in[2];
  const float* Wq1f  = (const float*)d_in[3];
  const float* Wk1f  = (const float*)d_in[4];
  const float* Wv1f  = (const float*)d_in[5];
  const float* Wo1f  = (const float*)d_in[6];
  const float* bo1   = (const float*)d_in[7];
  const float* g2    = (const float*)d_in[8];
  const float* Wq2f  = (const float*)d_in[9];
  const float* Wk2f  = (const float*)d_in[10];
  const float* Wv2f  = (const float*)d_in[11];
  const float* Wo2f  = (const float*)d_in[12];
  const float* bo2   = (const float*)d_in[13];
  const float* g3    = (const float*)d_in[14];
  const float* Wff1f = (const float*)d_in[15];
  const float* bff1  = (const float*)d_in[16];
  const float* Wff2f = (const float*)d_in[17];
  const float* bff2  = (const float*)d_in[18];

  char* wsp = (char*)d_ws;
  size_t off = 0;
  auto alloc = [&](size_t bytes) -> void* {
    void* p = wsp + off;
    off += (bytes + 255) & ~(size_t)255;
    return p;
  };

  bf16* xt    = (bf16*)alloc((size_t)8192 * 512 * 2);   // residual stream bf16
  bf16* x2    = (bf16*)alloc((size_t)8192 * 512 * 2);
  bf16* h     = (bf16*)alloc((size_t)8192 * 512 * 2);
  bf16* qkb   = (bf16*)alloc((size_t)8192 * 1024 * 2);
  bf16* qb    = (bf16*)alloc((size_t)8192 * 512 * 2);
  bf16* kb    = (bf16*)alloc((size_t)1024 * 512 * 2);
  bf16* vb    = (bf16*)alloc((size_t)8192 * 512 * 2);
  bf16* vb2   = (bf16*)alloc((size_t)1024 * 512 * 2);
  bf16* ao    = (bf16*)alloc((size_t)8192 * 512 * 2);
  bf16* ctxt  = (bf16*)alloc((size_t)1024 * 768 * 2);
  bf16* actb  = (bf16*)alloc((size_t)8192 * 2048 * 2);
  bf16* wqk1  = (bf16*)alloc((size_t)524288 * 2);
  bf16* wv1   = (bf16*)alloc((size_t)262144 * 2);
  bf16* wo1   = (bf16*)alloc((size_t)262144 * 2);
  bf16* wq2   = (bf16*)alloc((size_t)262144 * 2);
  bf16* wk2   = (bf16*)alloc((size_t)393216 * 2);
  bf16* wv2   = (bf16*)alloc((size_t)393216 * 2);
  bf16* wo2   = (bf16*)alloc((size_t)262144 * 2);
  bf16* wff1  = (bf16*)alloc((size_t)2097152 * 2);
  bf16* wff2  = (bf16*)alloc((size_t)1048576 * 2);

  {
    CvtPack p;
    const float* s[10] = {Wq1f, Wk1f, Wv1f, Wo1f, Wq2f, Wk2f, Wv2f, Wo2f, Wff1f, Wff2f};
    bf16* d[10] = {wqk1, wqk1 + 262144, wv1, wo1, wq2, wk2, wv2, wo2, wff1, wff2};
    int n[10] = {262144, 262144, 262144, 262144, 262144, 393216, 393216, 262144,
                 2097152, 1048576};
    int cum = 0;
    for (int i = 0; i < 10; i++) {
      p.src[i] = s[i]; p.dst[i] = d[i];
      cum += n[i] / 4; p.end4[i] = cum;
    }
    prologue<<<dim3(10240), dim3(256), 0, stream>>>(p, cum, x, xt, ctx, ctxt);
  }

  // ---- block 1: self attention (+ hoisted cross K/V) ----
  ln_rows<<<dim3(2048), dim3(256), 0, stream>>>(xt, g1, h);
  gemm_uber<<<dim3(1152), dim3(256), 0, stream>>>(
      h, wqk1, qkb, wv1, vb, ctxt, wk2, kb, wv2, vb2);
  flash_attn<<<dim3(16, 32), dim3(256), 0, stream>>>(qkb, 1024, qkb + 512, 1024,
                                                     vb, ao, 2048, 2048);
  launch_gemm<64>(ao, 0, wo1, 0, 8192, 512, 512, x2, 0, 512,
                  bo1, xt, 2, stream);

  // ---- block 2: cross attention ----
  ln_rows<<<dim3(2048), dim3(256), 0, stream>>>(x2, g2, h);
  launch_gemm<64>(h, 0, wq2, 0, 8192, 512, 512, qb, 0, 512,
                  nullptr, nullptr, 0, stream);
  flash_attn<<<dim3(16, 32), dim3(256), 0, stream>>>(qb, 512, kb, 512,
                                                     vb2, ao, 2048, 256);
  launch_gemm<64>(ao, 0, wo2, 0, 8192, 512, 512, x2, 0, 512,
                  bo2, x2, 2, stream);

  // ---- block 3: GEGLU FF; ff2 stores transposed directly to d_out ----
  ln_rows<<<dim3(2048), dim3(256), 0, stream>>>(x2, g3, h);
  gemm_geglu<<<dim3(64, 32), dim3(256), 0, stream>>>(
      h, wff1, wff1 + (long)2048 * 512, bff1, bff1 + 2048, actb, 512);
  launch_gemm<64>(actb, 0, wff2, 0, 8192, 512, 2048, d_out, 0, 512,
                  bff2, x2, 3, stream);
}